// Round 6
// baseline (425.443 us; speedup 1.0000x reference)
//
#include <hip/hip_runtime.h>
#include <stdint.h>

typedef unsigned short u16;
typedef unsigned int u32;
typedef int v4i __attribute__((ext_vector_type(4)));
typedef float v4f __attribute__((ext_vector_type(4)));
typedef short v8s __attribute__((ext_vector_type(8)));

#define Bn 2
#define Tn 2048
#define Cn 2048
#define Hn 16
#define HDn 128

__device__ __forceinline__ float b2f(u16 u) {
    u32 x = ((u32)u) << 16;
    float f;
    __builtin_memcpy(&f, &x, 4);
    return f;
}
__device__ __forceinline__ u16 f2b(float f) {
    u32 x;
    __builtin_memcpy(&x, &f, 4);
    u32 r = (x + 0x7fffu + ((x >> 16) & 1u)) >> 16;
    return (u16)r;
}
// pack two fp32 -> two bf16 in one op (RNE); no builtin on gfx950 (m240)
__device__ __forceinline__ u32 cvtpk(float a, float b) {
    u32 r;
    asm("v_cvt_pk_bf16_f32 %0, %1, %2" : "=v"(r) : "v"(a), "v"(b));
    return r;
}

__device__ __forceinline__ void async16(const void* g, void* l) {
    __builtin_amdgcn_global_load_lds(
        (const __attribute__((address_space(1))) u32*)g,
        (__attribute__((address_space(3))) u32*)l, 16, 0, 0);
}

// ---------- fused row quantization: 4 weight matrices + hidden ----------
__global__ __launch_bounds__(256) void quant_all(
    const float* __restrict__ w0, const float* __restrict__ w1,
    const float* __restrict__ w2, const float* __restrict__ w3,
    const float* __restrict__ hid, int8_t* __restrict__ Q,
    float* __restrict__ S) {
    int r = blockIdx.x;
    const float* src;
    int ro;
    if (r < 2048) { src = w0; ro = r; }
    else if (r < 4096) { src = w1; ro = r - 2048; }
    else if (r < 6144) { src = w2; ro = r - 4096; }
    else if (r < 8192) { src = w3; ro = r - 6144; }
    else { src = hid; ro = r - 8192; }
    const float* x = src + (size_t)ro * Cn;
    int tid = threadIdx.x;
    float4 v0 = ((const float4*)x)[tid * 2];
    float4 v1 = ((const float4*)x)[tid * 2 + 1];
    float a[8] = {v0.x, v0.y, v0.z, v0.w, v1.x, v1.y, v1.z, v1.w};
    float m = 0.f;
#pragma unroll
    for (int i = 0; i < 8; i++) m = fmaxf(m, fabsf(a[i]));
#pragma unroll
    for (int o = 32; o; o >>= 1) m = fmaxf(m, __shfl_xor(m, o));
    __shared__ float sm[4];
    if ((tid & 63) == 0) sm[tid >> 6] = m;
    __syncthreads();
    m = fmaxf(fmaxf(sm[0], sm[1]), fmaxf(sm[2], sm[3]));
    float s = m * (1.0f / 127.0f) + 1e-8f;
    if (tid == 0) S[r] = s;
    u32 lo = 0, hi = 0;
#pragma unroll
    for (int i = 0; i < 8; i++) {
        float q = rintf(fminf(127.f, fmaxf(-127.f, a[i] / s)));
        int qi = (int)q;
        u32 byte = (u32)(qi & 0xff);
        if (i < 4) lo |= byte << (8 * i);
        else hi |= byte << (8 * (i - 4));
    }
    u32* qp = (u32*)(Q + (size_t)r * Cn);
    qp[tid * 2] = lo;
    qp[tid * 2 + 1] = hi;
}

// ---------- row quantization (fp32, attention output O) ----------
__global__ __launch_bounds__(256) void quant_rows(const float* __restrict__ X,
                                                  int8_t* __restrict__ Q,
                                                  float* __restrict__ S) {
    int r = blockIdx.x;
    const float* x = X + (size_t)r * Cn;
    int tid = threadIdx.x;
    float4 v0 = ((const float4*)x)[tid * 2];
    float4 v1 = ((const float4*)x)[tid * 2 + 1];
    float a[8] = {v0.x, v0.y, v0.z, v0.w, v1.x, v1.y, v1.z, v1.w};
    float m = 0.f;
#pragma unroll
    for (int i = 0; i < 8; i++) m = fmaxf(m, fabsf(a[i]));
#pragma unroll
    for (int o = 32; o; o >>= 1) m = fmaxf(m, __shfl_xor(m, o));
    __shared__ float sm[4];
    if ((tid & 63) == 0) sm[tid >> 6] = m;
    __syncthreads();
    m = fmaxf(fmaxf(sm[0], sm[1]), fmaxf(sm[2], sm[3]));
    float s = m * (1.0f / 127.0f) + 1e-8f;
    if (tid == 0) S[r] = s;
    u32 lo = 0, hi = 0;
#pragma unroll
    for (int i = 0; i < 8; i++) {
        float q = rintf(fminf(127.f, fmaxf(-127.f, a[i] / s)));
        int qi = (int)q;
        u32 byte = (u32)(qi & 0xff);
        if (i < 4) lo |= byte << (8 * i);
        else hi |= byte << (8 * (i - 4));
    }
    u32* qp = (u32*)(Q + (size_t)r * Cn);
    qp[tid * 2] = lo;
    qp[tid * 2 + 1] = hi;
}

// ---------- int8 GEMM (REVERTED to R4 single-buffer: R5 dbuf was -7us;
// 2-phase is null at 128^2 tiles per m99/m100/m139 regime gate) ----------
__global__ __launch_bounds__(256) void gemm_i8(
    const int8_t* __restrict__ A, const int8_t* __restrict__ Bw,
    const float* __restrict__ sA, const float* __restrict__ sB,
    void* __restrict__ Co, long long bStride, long long sbStride,
    long long cStride, int fp32out) {
    int z = blockIdx.z;
    Bw += (size_t)z * bStride;
    sB += (size_t)z * sbStride;
    const int K = 2048, N = 2048;
    __shared__ int8_t As[128 * 64];
    __shared__ int8_t Bs[128 * 64];
    int m0 = blockIdx.x * 128, n0 = blockIdx.y * 128;
    int tid = threadIdx.x, w = tid >> 6, lane = tid & 63;
    int quad = lane >> 4, l15 = lane & 15;
    int wy = w >> 1, wx = w & 1;
    const v4i zi = {0, 0, 0, 0};
    v4i acc[4][4];
#pragma unroll
    for (int i = 0; i < 4; i++)
#pragma unroll
        for (int j = 0; j < 4; j++) acc[i][j] = zi;
    int lrow = lane >> 2;
    int slot = lane & 3;
    int srow = w * 32 + lrow;
    int klog = ((slot ^ (lrow & 3)) * 16);
    const int8_t* ga = A + (size_t)(m0 + srow) * K + klog;
    const int8_t* gb = Bw + (size_t)(n0 + srow) * K + klog;
    int8_t* la = &As[srow * 64 + slot * 16];
    int8_t* lb = &Bs[srow * 64 + slot * 16];
    for (int k0 = 0; k0 < K; k0 += 64) {
        async16(ga + k0, la);
        async16(ga + k0 + (size_t)16 * K, la + 16 * 64);
        async16(gb + k0, lb);
        async16(gb + k0 + (size_t)16 * K, lb + 16 * 64);
        __syncthreads();
        int swz = (quad ^ (l15 & 3)) * 16;
        v4i af[4], bf4[4];
#pragma unroll
        for (int i = 0; i < 4; i++)
            af[i] = *(const v4i*)&As[(wy * 64 + i * 16 + l15) * 64 + swz];
#pragma unroll
        for (int j = 0; j < 4; j++)
            bf4[j] = *(const v4i*)&Bs[(wx * 64 + j * 16 + l15) * 64 + swz];
#pragma unroll
        for (int i = 0; i < 4; i++)
#pragma unroll
            for (int j = 0; j < 4; j++)
                acc[i][j] = __builtin_amdgcn_mfma_i32_16x16x64_i8(
                    af[i], bf4[j], acc[i][j], 0, 0, 0);
        __syncthreads();
    }
#pragma unroll
    for (int i = 0; i < 4; i++) {
        int mb = m0 + wy * 64 + i * 16 + quad * 4;
        float s0 = sA[mb], s1 = sA[mb + 1], s2 = sA[mb + 2], s3 = sA[mb + 3];
#pragma unroll
        for (int j = 0; j < 4; j++) {
            int n = n0 + wx * 64 + j * 16 + l15;
            float sb = sB[n];
            if (fp32out) {
                float* cp = (float*)Co + (size_t)cStride * z + (size_t)mb * N + n;
                cp[0] = (float)acc[i][j][0] * s0 * sb;
                cp[N] = (float)acc[i][j][1] * s1 * sb;
                cp[2 * N] = (float)acc[i][j][2] * s2 * sb;
                cp[3 * N] = (float)acc[i][j][3] * s3 * sb;
            } else {
                u16* cp = (u16*)Co + (size_t)cStride * z + (size_t)mb * N + n;
                cp[0] = f2b((float)acc[i][j][0] * s0 * sb);
                cp[N] = f2b((float)acc[i][j][1] * s1 * sb);
                cp[2 * N] = f2b((float)acc[i][j][2] * s2 * sb);
                cp[3 * N] = f2b((float)acc[i][j][3] * s3 * sb);
            }
        }
    }
}

// ---------- fused RMSNorm + RoPE ----------
// Q scale folds 1/sqrt(HD) AND log2(e) (flash v8 uses exp2 directly).
__global__ __launch_bounds__(256) void norm_rope2(u16* __restrict__ Qb,
                                                  u16* __restrict__ Kb,
                                                  const float* __restrict__ qg,
                                                  const float* __restrict__ kg,
                                                  const float* __restrict__ cs,
                                                  const float* __restrict__ sn) {
    int row = blockIdx.x;
    int isq = row < 4096;
    row &= 4095;
    u16* x = (isq ? Qb : Kb) + (size_t)row * Cn;
    const float* g = isq ? qg : kg;
    float ps = isq ? 0.1275174306f : 1.0f;  // log2e/sqrt(128)
    int t = row & (Tn - 1);
    int tid = threadIdx.x;
    uint4 raw = ((const uint4*)x)[tid];
    u16 us[8];
    us[0] = raw.x & 0xffff; us[1] = raw.x >> 16;
    us[2] = raw.y & 0xffff; us[3] = raw.y >> 16;
    us[4] = raw.z & 0xffff; us[5] = raw.z >> 16;
    us[6] = raw.w & 0xffff; us[7] = raw.w >> 16;
    float v[8];
#pragma unroll
    for (int i = 0; i < 8; i++) v[i] = b2f(us[i]);
    float ss = 0.f;
#pragma unroll
    for (int i = 0; i < 8; i++) ss += v[i] * v[i];
#pragma unroll
    for (int o = 32; o; o >>= 1) ss += __shfl_xor(ss, o);
    __shared__ float sm[4];
    if ((tid & 63) == 0) sm[tid >> 6] = ss;
    __syncthreads();
    ss = sm[0] + sm[1] + sm[2] + sm[3];
    float r = rsqrtf(ss * (1.f / 2048.f) + 1e-6f) * ps;
    float4 g0 = ((const float4*)g)[tid * 2];
    float4 g1 = ((const float4*)g)[tid * 2 + 1];
    float n[8];
    n[0] = v[0] * r * g0.x; n[1] = v[1] * r * g0.y;
    n[2] = v[2] * r * g0.z; n[3] = v[3] * r * g0.w;
    n[4] = v[4] * r * g1.x; n[5] = v[5] * r * g1.y;
    n[6] = v[6] * r * g1.z; n[7] = v[7] * r * g1.w;
    int pi = (tid & 15) * 4;
    float4 c4 = *(const float4*)(cs + t * 64 + pi);
    float4 s4 = *(const float4*)(sn + t * 64 + pi);
    float o[8];
    o[0] = n[0] * c4.x - n[1] * s4.x; o[1] = n[0] * s4.x + n[1] * c4.x;
    o[2] = n[2] * c4.y - n[3] * s4.y; o[3] = n[2] * s4.y + n[3] * c4.y;
    o[4] = n[4] * c4.z - n[5] * s4.z; o[5] = n[4] * s4.z + n[5] * c4.z;
    o[6] = n[6] * c4.w - n[7] * s4.w; o[7] = n[6] * s4.w + n[7] * c4.w;
    uint4 out;
    out.x = (u32)f2b(o[0]) | ((u32)f2b(o[1]) << 16);
    out.y = (u32)f2b(o[2]) | ((u32)f2b(o[3]) << 16);
    out.z = (u32)f2b(o[4]) | ((u32)f2b(o[5]) << 16);
    out.w = (u32)f2b(o[6]) | ((u32)f2b(o[7]) << 16);
    ((uint4*)x)[tid] = out;
}

// ---------- V transpose: (b,t,h,d) bf16 -> Vt[b][h][d][t] ----------
__global__ __launch_bounds__(256) void vtrans(const u16* __restrict__ V,
                                              u16* __restrict__ Vt) {
    int bh = blockIdx.y;
    int b = bh >> 4, h = bh & 15;
    int t0 = blockIdx.x * 64;
    __shared__ u32 tile[64][133];
    int tid = threadIdx.x;
    int r = tid >> 2, seg = (tid & 3) * 32;
    const uint4* src =
        (const uint4*)(V + ((size_t)b * Tn + t0 + r) * Cn + h * HDn + seg);
#pragma unroll
    for (int i = 0; i < 4; i++) {
        uint4 u = src[i];
        u32 uu[4] = {u.x, u.y, u.z, u.w};
#pragma unroll
        for (int j = 0; j < 4; j++) {
            tile[r][seg + i * 8 + j * 2] = uu[j] & 0xffff;
            tile[r][seg + i * 8 + j * 2 + 1] = uu[j] >> 16;
        }
    }
    __syncthreads();
    int d = tid >> 1, tseg = (tid & 1) * 32;
    u16* dst = Vt + ((size_t)bh * HDn + d) * Tn + t0 + tseg;
#pragma unroll
    for (int i = 0; i < 4; i++) {
        u32 p0 = tile[tseg + i * 8 + 0][d] | (tile[tseg + i * 8 + 1][d] << 16);
        u32 p1 = tile[tseg + i * 8 + 2][d] | (tile[tseg + i * 8 + 3][d] << 16);
        u32 p2 = tile[tseg + i * 8 + 4][d] | (tile[tseg + i * 8 + 5][d] << 16);
        u32 p3 = tile[tseg + i * 8 + 6][d] | (tile[tseg + i * 8 + 7][d] << 16);
        ((uint4*)dst)[i] = make_uint4(p0, p1, p2, p3);
    }
}

// ---------- flash v8: per-wave q-ownership, swapped QK, wave-private P,
// ONE barrier per tile (K staging only). ----------
// Wave w owns q-rows qt*64 + w*16 .. +15 end-to-end:
//   QK: sacc[kb] = mfma(Kfrag[kb], Qfrag) -> S[key][q], col=q=l15
//   exp2 (log2e pre-folded into Q), cvt_pk -> wave-private LDS scratch
//   (same-wave RAW, no barrier), read back as PV A-frags
//   PV: oacc[nb] += mfma(P, Vfrag[nb]) over all 8 d-blocks
// V: global->reg, issued FIRST in tile (oldest vmem -> compiler waits
// vmcnt(4), K-prefetch stays in flight; R3 lesson). K: async dbuf.
__global__ __launch_bounds__(256, 3) void flash(const u16* __restrict__ Qb,
                                                const u16* __restrict__ Kb,
                                                const u16* __restrict__ Vt,
                                                const int* __restrict__ mask,
                                                float* __restrict__ O) {
    int id = blockIdx.x;
    int bh = (id & 7) + 8 * (id >> 8);  // XCD-aware (proven: FETCH 93->21MB)
    int qt = (id >> 3) & 31;
    int b = bh >> 4, h = bh & 15;
    int L = mask[b];
    int nkfull = L >> 6;
    int nk = (L + 63) >> 6;
    int rem = L & 63;
    __shared__ u16 Ks[2][64 * 128];
    __shared__ u16 Pw[4][16 * 64];  // wave-private P scratch (XOR-swizzled)
    int tid = threadIdx.x, w = tid >> 6, lane = tid & 63;
    int quad = lane >> 4, l15 = lane & 15;
    int sw = l15 & 7;

    // Q B-fragments (swapped QK): this wave's 16 q-rows only.
    const u16* qrow =
        Qb + ((size_t)b * Tn + qt * 64 + w * 16 + l15) * Cn + h * HDn + quad * 8;
    v8s qf[4];
#pragma unroll
    for (int kk = 0; kk < 4; kk++) qf[kk] = *(const v8s*)(qrow + kk * 32);

    // K async staging geometry (XOR source gather -> conflict-free reads)
    const u16* ksp[4];
    int kdo[4];
#pragma unroll
    for (int cc = 0; cc < 4; cc++) {
        int c = w * 4 + cc;
        int rk = c * 4 + (lane >> 4);
        int sk = lane & 15;
        int lgk = sk ^ (rk & 7);
        ksp[cc] = Kb + ((size_t)b * Tn + rk) * Cn + h * HDn + lgk * 8;
        kdo[cc] = rk * 128 + sk * 8;
    }

    // V B-frag base: lane (quad,l15) reads Vt[bh][nb*16+l15][t=kt*64+ks*32+quad*8]
    const u16* vrun = Vt + ((size_t)bh * HDn + l15) * Tn + quad * 8;

    float rs = 0.f;
    const v4f zf = {0.f, 0.f, 0.f, 0.f};
    v4f oacc[8];
#pragma unroll
    for (int nb = 0; nb < 8; nb++) oacc[nb] = zf;

    // prologue: stage K tile 0
#pragma unroll
    for (int cc = 0; cc < 4; cc++) {
        async16(ksp[cc], &Ks[0][kdo[cc]]);
        ksp[cc] += (size_t)64 * Cn;
    }
    __syncthreads();

    int cur = 0;
    for (int kt = 0; kt < nk; kt++) {
        // V loads FIRST (oldest vmem)
        v8s vv[2][8];
#pragma unroll
        for (int ks = 0; ks < 2; ks++)
#pragma unroll
            for (int nb = 0; nb < 8; nb++)
                vv[ks][nb] =
                    *(const v8s*)(vrun + (size_t)(nb * 16) * Tn + ks * 32);
        vrun += 64;
        __builtin_amdgcn_sched_barrier(0);  // pin V issue before K prefetch
        if (kt + 1 < nk) {
#pragma unroll
            for (int cc = 0; cc < 4; cc++) {
                async16(ksp[cc], &Ks[cur ^ 1][kdo[cc]]);
                ksp[cc] += (size_t)64 * Cn;
            }
        }
        // swapped QK: sacc[kb] row = key = quad*4+r2 (+kb*16), col = q = l15
        v4f sacc[4] = {zf, zf, zf, zf};
        const u16* kbase = &Ks[cur][0];
#pragma unroll
        for (int kk = 0; kk < 4; kk++) {
#pragma unroll
            for (int kb = 0; kb < 4; kb++) {
                v8s kf = *(const v8s*)(kbase + (kb * 16 + l15) * 128 +
                                       (((kk * 4 + quad) ^ sw) << 3));
                sacc[kb] = __builtin_amdgcn_mfma_f32_16x16x32_bf16(
                    kf, qf[kk], sacc[kb], 0, 0, 0);
            }
        }
        // exp2 + pack + wave-private store: P[q=l15][key] (chunk-XOR layout)
#pragma unroll
        for (int kb = 0; kb < 4; kb++) {
            float p0, p1, p2, p3;
            if (kt < nkfull) {
                p0 = exp2f(sacc[kb][0]);
                p1 = exp2f(sacc[kb][1]);
                p2 = exp2f(sacc[kb][2]);
                p3 = exp2f(sacc[kb][3]);
            } else {
                int key = kb * 16 + quad * 4;
                p0 = (key + 0 < rem) ? exp2f(sacc[kb][0]) : 0.f;
                p1 = (key + 1 < rem) ? exp2f(sacc[kb][1]) : 0.f;
                p2 = (key + 2 < rem) ? exp2f(sacc[kb][2]) : 0.f;
                p3 = (key + 3 < rem) ? exp2f(sacc[kb][3]) : 0.f;
            }
            rs += (p0 + p1) + (p2 + p3);
            int ch = kb * 2 + (quad >> 1);
            u32* dst = (u32*)&Pw[w][l15 * 64 + ((ch ^ sw) << 3) + ((quad & 1) << 2)];
            dst[0] = cvtpk(p0, p1);
            dst[1] = cvtpk(p2, p3);
        }
        // PV: A = P rows (lane=q=l15, keys quad*8..+7), B = V regs
#pragma unroll
        for (int ks = 0; ks < 2; ks++) {
            v8s pa = *(const v8s*)&Pw[w][l15 * 64 + (((ks * 4 + quad) ^ sw) << 3)];
#pragma unroll
            for (int nb = 0; nb < 8; nb++)
                oacc[nb] = __builtin_amdgcn_mfma_f32_16x16x32_bf16(
                    pa, vv[ks][nb], oacc[nb], 0, 0, 0);
        }
        __syncthreads();  // K(kt+1) staged; Ks[cur] free for next prefetch
        cur ^= 1;
    }
    // softmax denominators: lane holds partial for q = l15 over its 16 keys;
    // reduce across the 4 quads, then redistribute to C-layout rows.
    rs += __shfl_xor(rs, 16);
    rs += __shfl_xor(rs, 32);
    float rinv = 1.f / rs;
    float inv[4];
#pragma unroll
    for (int r2 = 0; r2 < 4; r2++) inv[r2] = __shfl(rinv, quad * 4 + r2, 16);
    // O write: row q = qt*64 + w*16 + quad*4 + r2, col d = h*128 + nb*16 + l15
    int qrow0 = qt * 64 + w * 16 + quad * 4;
#pragma unroll
    for (int r2 = 0; r2 < 4; r2++) {
        float* orow = O + ((size_t)b * Tn + qrow0 + r2) * Cn + h * HDn + l15;
#pragma unroll
        for (int nb = 0; nb < 8; nb++) orow[nb * 16] = oacc[nb][r2] * inv[r2];
    }
}

extern "C" void kernel_launch(void* const* d_in, const int* in_sizes, int n_in,
                              void* d_out, int out_size, void* d_ws,
                              size_t ws_size, hipStream_t stream) {
    const float* hidden = (const float*)d_in[0];
    const int* mask = (const int*)d_in[1];
    const float* wq = (const float*)d_in[2];
    const float* wk = (const float*)d_in[3];
    const float* wv = (const float*)d_in[4];
    const float* wo = (const float*)d_in[5];
    const float* qg = (const float*)d_in[6];
    const float* kg = (const float*)d_in[7];
    const float* cs = (const float*)d_in[8];
    const float* sn = (const float*)d_in[9];

    char* ws = (char*)d_ws;
    int8_t* q8 = (int8_t*)(ws);                  // 24 MiB: wq,wk,wv,wo + hidden
    float* sAll = (float*)(ws + 25165824);       // 12288 fp32 scales
    u16* qb = (u16*)(ws + 25214976);             // Q bf16 (B,T,C)
    u16* kb = (u16*)(ws + 41992192);             // K bf16
    u16* vb = (u16*)(ws + 58769408);             // V bf16
    u16* vt = (u16*)(ws + 75546624);             // V^T bf16 (B,H,HD,T)
    float* Obuf = (float*)(ws + 92323840);       // O fp32 (B,T,C)
    int8_t* hid8 = q8 + 16777216;                // hidden int8 (reused for O)
    float* sx = sAll + 8192;                     // hidden scales (reused for O)

    quant_all<<<12288, 256, 0, stream>>>(wq, wk, wv, wo, hidden, q8, sAll);

    gemm_i8<<<dim3(32, 16, 3), 256, 0, stream>>>(hid8, q8, sx, sAll, (void*)qb,
                                                 4194304LL, 2048LL, 8388608LL, 0);

    norm_rope2<<<8192, 256, 0, stream>>>(qb, kb, qg, kg, cs, sn);
    vtrans<<<dim3(32, 32), 256, 0, stream>>>(vb, vt);

    flash<<<dim3(1024), 256, 0, stream>>>(qb, kb, vt, mask, Obuf);

    quant_rows<<<4096, 256, 0, stream>>>(Obuf, hid8, sx);
    gemm_i8<<<dim3(32, 16, 1), 256, 0, stream>>>(hid8, q8 + 12582912, sx,
                                                 sAll + 6144, d_out, 0LL, 0LL,
                                                 0LL, 1);
}

// Round 7
// 361.578 us; speedup vs baseline: 1.1766x; 1.1766x over previous
//
#include <hip/hip_runtime.h>
#include <stdint.h>

typedef unsigned short u16;
typedef unsigned int u32;
typedef int v4i __attribute__((ext_vector_type(4)));
typedef float v4f __attribute__((ext_vector_type(4)));
typedef short v8s __attribute__((ext_vector_type(8)));

#define Bn 2
#define Tn 2048
#define Cn 2048
#define Hn 16
#define HDn 128

__device__ __forceinline__ float b2f(u16 u) {
    u32 x = ((u32)u) << 16;
    float f;
    __builtin_memcpy(&f, &x, 4);
    return f;
}
__device__ __forceinline__ u16 f2b(float f) {
    u32 x;
    __builtin_memcpy(&x, &f, 4);
    u32 r = (x + 0x7fffu + ((x >> 16) & 1u)) >> 16;
    return (u16)r;
}

__device__ __forceinline__ void async16(const void* g, void* l) {
    __builtin_amdgcn_global_load_lds(
        (const __attribute__((address_space(1))) u32*)g,
        (__attribute__((address_space(3))) u32*)l, 16, 0, 0);
}

// ---------- fused row quantization: 4 weight matrices + hidden ----------
__global__ __launch_bounds__(256) void quant_all(
    const float* __restrict__ w0, const float* __restrict__ w1,
    const float* __restrict__ w2, const float* __restrict__ w3,
    const float* __restrict__ hid, int8_t* __restrict__ Q,
    float* __restrict__ S) {
    int r = blockIdx.x;
    const float* src;
    int ro;
    if (r < 2048) { src = w0; ro = r; }
    else if (r < 4096) { src = w1; ro = r - 2048; }
    else if (r < 6144) { src = w2; ro = r - 4096; }
    else if (r < 8192) { src = w3; ro = r - 6144; }
    else { src = hid; ro = r - 8192; }
    const float* x = src + (size_t)ro * Cn;
    int tid = threadIdx.x;
    float4 v0 = ((const float4*)x)[tid * 2];
    float4 v1 = ((const float4*)x)[tid * 2 + 1];
    float a[8] = {v0.x, v0.y, v0.z, v0.w, v1.x, v1.y, v1.z, v1.w};
    float m = 0.f;
#pragma unroll
    for (int i = 0; i < 8; i++) m = fmaxf(m, fabsf(a[i]));
#pragma unroll
    for (int o = 32; o; o >>= 1) m = fmaxf(m, __shfl_xor(m, o));
    __shared__ float sm[4];
    if ((tid & 63) == 0) sm[tid >> 6] = m;
    __syncthreads();
    m = fmaxf(fmaxf(sm[0], sm[1]), fmaxf(sm[2], sm[3]));
    float s = m * (1.0f / 127.0f) + 1e-8f;
    if (tid == 0) S[r] = s;
    u32 lo = 0, hi = 0;
#pragma unroll
    for (int i = 0; i < 8; i++) {
        float q = rintf(fminf(127.f, fmaxf(-127.f, a[i] / s)));
        int qi = (int)q;
        u32 byte = (u32)(qi & 0xff);
        if (i < 4) lo |= byte << (8 * i);
        else hi |= byte << (8 * (i - 4));
    }
    u32* qp = (u32*)(Q + (size_t)r * Cn);
    qp[tid * 2] = lo;
    qp[tid * 2 + 1] = hi;
}

// ---------- row quantization (fp32, attention output O) ----------
__global__ __launch_bounds__(256) void quant_rows(const float* __restrict__ X,
                                                  int8_t* __restrict__ Q,
                                                  float* __restrict__ S) {
    int r = blockIdx.x;
    const float* x = X + (size_t)r * Cn;
    int tid = threadIdx.x;
    float4 v0 = ((const float4*)x)[tid * 2];
    float4 v1 = ((const float4*)x)[tid * 2 + 1];
    float a[8] = {v0.x, v0.y, v0.z, v0.w, v1.x, v1.y, v1.z, v1.w};
    float m = 0.f;
#pragma unroll
    for (int i = 0; i < 8; i++) m = fmaxf(m, fabsf(a[i]));
#pragma unroll
    for (int o = 32; o; o >>= 1) m = fmaxf(m, __shfl_xor(m, o));
    __shared__ float sm[4];
    if ((tid & 63) == 0) sm[tid >> 6] = m;
    __syncthreads();
    m = fmaxf(fmaxf(sm[0], sm[1]), fmaxf(sm[2], sm[3]));
    float s = m * (1.0f / 127.0f) + 1e-8f;
    if (tid == 0) S[r] = s;
    u32 lo = 0, hi = 0;
#pragma unroll
    for (int i = 0; i < 8; i++) {
        float q = rintf(fminf(127.f, fmaxf(-127.f, a[i] / s)));
        int qi = (int)q;
        u32 byte = (u32)(qi & 0xff);
        if (i < 4) lo |= byte << (8 * i);
        else hi |= byte << (8 * (i - 4));
    }
    u32* qp = (u32*)(Q + (size_t)r * Cn);
    qp[tid * 2] = lo;
    qp[tid * 2 + 1] = hi;
}

// ---------- int8 GEMM v3: 256x128 tile, 8 waves, 2-deep prefetch with
// COUNTED vmcnt (T4) via raw s_barrier. Per K-step:
//   vmcnt(3) (tile k landed; tile k+1's 3 loads stay in flight)
//   barrier -> ds_read frags(buf k&1) -> 16 MFMA
//   barrier (all reads of buf fenced) -> stage tile k+2 into buf k&1
// Mid-loop vmcnt is never 0; stage has a full K-step (~300cy) to land.
// Per-wave math/swizzle identical to the proven 128^2 kernel.
__global__ __launch_bounds__(512, 4) void gemm_i8(
    const int8_t* __restrict__ A, const int8_t* __restrict__ Bw,
    const float* __restrict__ sA, const float* __restrict__ sB,
    void* __restrict__ Co, long long bStride, long long sbStride,
    long long cStride, int fp32out) {
    int z = blockIdx.z;
    Bw += (size_t)z * bStride;
    sB += (size_t)z * sbStride;
    const int K = 2048, N = 2048;
    __shared__ int8_t As[2][256 * 64];
    __shared__ int8_t Bs[2][128 * 64];
    int m0 = blockIdx.x * 256, n0 = blockIdx.y * 128;
    int tid = threadIdx.x, w = tid >> 6, lane = tid & 63;
    int quad = lane >> 4, l15 = lane & 15;
    int wy = w >> 1, wx = w & 1;
    const v4i zi = {0, 0, 0, 0};
    v4i acc[4][4];
#pragma unroll
    for (int i = 0; i < 4; i++)
#pragma unroll
        for (int j = 0; j < 4; j++) acc[i][j] = zi;
    int lrow = lane >> 2;
    int slot = lane & 3;
    int arow = w * 32 + lrow;  // 0..255 across 8 waves (two halves via +16)
    int brow = w * 16 + lrow;  // 0..127
    const int8_t* ga = A + (size_t)(m0 + arow) * K + ((slot ^ (arow & 3)) * 16);
    const int8_t* gb = Bw + (size_t)(n0 + brow) * K + ((slot ^ (brow & 3)) * 16);
    int la = arow * 64 + slot * 16;
    int lb = brow * 64 + slot * 16;
#define GSTAGE(BI, KS)                                                       \
    do {                                                                     \
        async16(ga + (KS) * 64, &As[BI][la]);                                \
        async16(ga + (KS) * 64 + (size_t)16 * K, &As[BI][la + 16 * 64]);     \
        async16(gb + (KS) * 64, &Bs[BI][lb]);                                \
    } while (0)
    GSTAGE(0, 0);
    GSTAGE(1, 1);
    int swz = (quad ^ (l15 & 3)) * 16;
    for (int k = 0; k < 32; ++k) {
        if (k < 31)
            asm volatile("s_waitcnt vmcnt(3)" ::: "memory");
        else
            asm volatile("s_waitcnt vmcnt(0)" ::: "memory");
        __builtin_amdgcn_s_barrier();
        __builtin_amdgcn_sched_barrier(0);
        int bi = k & 1;
        v4i af[4], bf4[4];
#pragma unroll
        for (int i = 0; i < 4; i++)
            af[i] = *(const v4i*)&As[bi][(wy * 64 + i * 16 + l15) * 64 + swz];
#pragma unroll
        for (int j = 0; j < 4; j++)
            bf4[j] = *(const v4i*)&Bs[bi][(wx * 64 + j * 16 + l15) * 64 + swz];
#pragma unroll
        for (int i = 0; i < 4; i++)
#pragma unroll
            for (int j = 0; j < 4; j++)
                acc[i][j] = __builtin_amdgcn_mfma_i32_16x16x64_i8(
                    af[i], bf4[j], acc[i][j], 0, 0, 0);
        __builtin_amdgcn_sched_barrier(0);
        __builtin_amdgcn_s_barrier();
        __builtin_amdgcn_sched_barrier(0);
        if (k < 30) GSTAGE(bi, k + 2);
    }
#pragma unroll
    for (int i = 0; i < 4; i++) {
        int mb = m0 + wy * 64 + i * 16 + quad * 4;
        float s0 = sA[mb], s1 = sA[mb + 1], s2 = sA[mb + 2], s3 = sA[mb + 3];
#pragma unroll
        for (int j = 0; j < 4; j++) {
            int n = n0 + wx * 64 + j * 16 + l15;
            float sb = sB[n];
            if (fp32out) {
                float* cp = (float*)Co + (size_t)cStride * z + (size_t)mb * N + n;
                cp[0] = (float)acc[i][j][0] * s0 * sb;
                cp[N] = (float)acc[i][j][1] * s1 * sb;
                cp[2 * N] = (float)acc[i][j][2] * s2 * sb;
                cp[3 * N] = (float)acc[i][j][3] * s3 * sb;
            } else {
                u16* cp = (u16*)Co + (size_t)cStride * z + (size_t)mb * N + n;
                cp[0] = f2b((float)acc[i][j][0] * s0 * sb);
                cp[N] = f2b((float)acc[i][j][1] * s1 * sb);
                cp[2 * N] = f2b((float)acc[i][j][2] * s2 * sb);
                cp[3 * N] = f2b((float)acc[i][j][3] * s3 * sb);
            }
        }
    }
}

// ---------- fused RMSNorm + RoPE ----------
// Q scale folds 1/sqrt(HD) AND log2(e) (flash uses exp2 directly).
__global__ __launch_bounds__(256) void norm_rope2(u16* __restrict__ Qb,
                                                  u16* __restrict__ Kb,
                                                  const float* __restrict__ qg,
                                                  const float* __restrict__ kg,
                                                  const float* __restrict__ cs,
                                                  const float* __restrict__ sn) {
    int row = blockIdx.x;
    int isq = row < 4096;
    row &= 4095;
    u16* x = (isq ? Qb : Kb) + (size_t)row * Cn;
    const float* g = isq ? qg : kg;
    float ps = isq ? 0.1275174306f : 1.0f;  // log2e/sqrt(128)
    int t = row & (Tn - 1);
    int tid = threadIdx.x;
    uint4 raw = ((const uint4*)x)[tid];
    u16 us[8];
    us[0] = raw.x & 0xffff; us[1] = raw.x >> 16;
    us[2] = raw.y & 0xffff; us[3] = raw.y >> 16;
    us[4] = raw.z & 0xffff; us[5] = raw.z >> 16;
    us[6] = raw.w & 0xffff; us[7] = raw.w >> 16;
    float v[8];
#pragma unroll
    for (int i = 0; i < 8; i++) v[i] = b2f(us[i]);
    float ss = 0.f;
#pragma unroll
    for (int i = 0; i < 8; i++) ss += v[i] * v[i];
#pragma unroll
    for (int o = 32; o; o >>= 1) ss += __shfl_xor(ss, o);
    __shared__ float sm[4];
    if ((tid & 63) == 0) sm[tid >> 6] = ss;
    __syncthreads();
    ss = sm[0] + sm[1] + sm[2] + sm[3];
    float r = rsqrtf(ss * (1.f / 2048.f) + 1e-6f) * ps;
    float4 g0 = ((const float4*)g)[tid * 2];
    float4 g1 = ((const float4*)g)[tid * 2 + 1];
    float n[8];
    n[0] = v[0] * r * g0.x; n[1] = v[1] * r * g0.y;
    n[2] = v[2] * r * g0.z; n[3] = v[3] * r * g0.w;
    n[4] = v[4] * r * g1.x; n[5] = v[5] * r * g1.y;
    n[6] = v[6] * r * g1.z; n[7] = v[7] * r * g1.w;
    int pi = (tid & 15) * 4;
    float4 c4 = *(const float4*)(cs + t * 64 + pi);
    float4 s4 = *(const float4*)(sn + t * 64 + pi);
    float o[8];
    o[0] = n[0] * c4.x - n[1] * s4.x; o[1] = n[0] * s4.x + n[1] * c4.x;
    o[2] = n[2] * c4.y - n[3] * s4.y; o[3] = n[2] * s4.y + n[3] * c4.y;
    o[4] = n[4] * c4.z - n[5] * s4.z; o[5] = n[4] * s4.z + n[5] * c4.z;
    o[6] = n[6] * c4.w - n[7] * s4.w; o[7] = n[6] * s4.w + n[7] * c4.w;
    uint4 out;
    out.x = (u32)f2b(o[0]) | ((u32)f2b(o[1]) << 16);
    out.y = (u32)f2b(o[2]) | ((u32)f2b(o[3]) << 16);
    out.z = (u32)f2b(o[4]) | ((u32)f2b(o[5]) << 16);
    out.w = (u32)f2b(o[6]) | ((u32)f2b(o[7]) << 16);
    ((uint4*)x)[tid] = out;
}

// ---------- V transpose: (b,t,h,d) bf16 -> Vt[b][h][d][t] ----------
__global__ __launch_bounds__(256) void vtrans(const u16* __restrict__ V,
                                              u16* __restrict__ Vt) {
    int bh = blockIdx.y;
    int b = bh >> 4, h = bh & 15;
    int t0 = blockIdx.x * 64;
    __shared__ u32 tile[64][133];
    int tid = threadIdx.x;
    int r = tid >> 2, seg = (tid & 3) * 32;
    const uint4* src =
        (const uint4*)(V + ((size_t)b * Tn + t0 + r) * Cn + h * HDn + seg);
#pragma unroll
    for (int i = 0; i < 4; i++) {
        uint4 u = src[i];
        u32 uu[4] = {u.x, u.y, u.z, u.w};
#pragma unroll
        for (int j = 0; j < 4; j++) {
            tile[r][seg + i * 8 + j * 2] = uu[j] & 0xffff;
            tile[r][seg + i * 8 + j * 2 + 1] = uu[j] >> 16;
        }
    }
    __syncthreads();
    int d = tid >> 1, tseg = (tid & 1) * 32;
    u16* dst = Vt + ((size_t)bh * HDn + d) * Tn + t0 + tseg;
#pragma unroll
    for (int i = 0; i < 4; i++) {
        u32 p0 = tile[tseg + i * 8 + 0][d] | (tile[tseg + i * 8 + 1][d] << 16);
        u32 p1 = tile[tseg + i * 8 + 2][d] | (tile[tseg + i * 8 + 3][d] << 16);
        u32 p2 = tile[tseg + i * 8 + 4][d] | (tile[tseg + i * 8 + 5][d] << 16);
        u32 p3 = tile[tseg + i * 8 + 6][d] | (tile[tseg + i * 8 + 7][d] << 16);
        ((uint4*)dst)[i] = make_uint4(p0, p1, p2, p3);
    }
}

// ---------- flash v7 (reverted to R5 best, 82.8us) + exp2f ----------
__global__ __launch_bounds__(256, 3) void flash(const u16* __restrict__ Qb,
                                                const u16* __restrict__ Kb,
                                                const u16* __restrict__ Vt,
                                                const int* __restrict__ mask,
                                                float* __restrict__ O) {
    int id = blockIdx.x;
    int bh = (id & 7) + 8 * (id >> 8);  // XCD-aware (proven: FETCH 93->21MB)
    int qt = (id >> 3) & 31;
    int b = bh >> 4, h = bh & 15;
    int L = mask[b];
    int nkfull = L >> 6;
    int nk = (L + 63) >> 6;
    __shared__ u16 Ks[2][64 * 128];
    __shared__ u16 Ps[2][64 * 72];
    __shared__ float sred[256];
    __shared__ float sinv[64];
    int tid = threadIdx.x, w = tid >> 6, lane = tid & 63;
    int quad = lane >> 4, l15 = lane & 15;

    v8s aq[4][4];
#pragma unroll
    for (int i = 0; i < 4; i++)
#pragma unroll
        for (int kk = 0; kk < 4; kk++)
            aq[i][kk] = *(const v8s*)(Qb +
                                      ((size_t)b * Tn + qt * 64 + i * 16 + l15) * Cn +
                                      h * HDn + kk * 32 + quad * 8);

    const u16* ksp[4];
    int kdo[4];
#pragma unroll
    for (int cc = 0; cc < 4; cc++) {
        int c = w * 4 + cc;
        int rk = c * 4 + (lane >> 4);
        int sk = lane & 15;
        int lgk = sk ^ (rk & 7);
        ksp[cc] = Kb + ((size_t)b * Tn + rk) * Cn + h * HDn + lgk * 8;
        kdo[cc] = rk * 128 + sk * 8;
    }

    const u16* vp0 = Vt + ((size_t)bh * HDn + 2 * w * 16 + l15) * Tn + quad * 8;
    const u16* vp1 = vp0 + 16 * Tn;

    float sum16[16];
#pragma unroll
    for (int j = 0; j < 16; j++) sum16[j] = 0.f;
    const v4f zf = {0.f, 0.f, 0.f, 0.f};
    v4f oacc[4][2];
#pragma unroll
    for (int m = 0; m < 4; m++) {
        oacc[m][0] = zf;
        oacc[m][1] = zf;
    }

#pragma unroll
    for (int cc = 0; cc < 4; cc++) {
        async16(ksp[cc], &Ks[0][kdo[cc]]);
        ksp[cc] += (size_t)64 * Cn;
    }
    __syncthreads();

    int cur = 0;
    for (int kt = 0; kt < nk; kt++) {
        if (kt + 1 < nk) {
#pragma unroll
            for (int cc = 0; cc < 4; cc++) {
                async16(ksp[cc], &Ks[cur ^ 1][kdo[cc]]);
                ksp[cc] += (size_t)64 * Cn;
            }
        }
        v8s bv00 = *(const v8s*)(vp0);
        v8s bv10 = *(const v8s*)(vp0 + 32);
        v8s bv01 = *(const v8s*)(vp1);
        v8s bv11 = *(const v8s*)(vp1 + 32);
        vp0 += 64;
        vp1 += 64;
        v4f sacc[4] = {zf, zf, zf, zf};
        const u16* krow = &Ks[cur][(w * 16 + l15) * 128];
#pragma unroll
        for (int kk = 0; kk < 4; kk++) {
            v8s bk = *(const v8s*)(krow + ((((kk * 4 + quad) ^ (l15 & 7))) << 3));
#pragma unroll
            for (int i = 0; i < 4; i++)
                sacc[i] = __builtin_amdgcn_mfma_f32_16x16x32_bf16(aq[i][kk], bk,
                                                                  sacc[i], 0, 0, 0);
        }
        bool valid = (kt < nkfull) || ((kt * 64 + w * 16 + l15) < L);
#pragma unroll
        for (int i = 0; i < 4; i++)
#pragma unroll
            for (int r2 = 0; r2 < 4; r2++) {
                float p = valid ? exp2f(sacc[i][r2]) : 0.f;
                sum16[i * 4 + r2] += p;
                Ps[cur][(i * 16 + quad * 4 + r2) * 72 + w * 16 + l15] = f2b(p);
            }
        __syncthreads();  // Ps[cur] visible; K(kt+1) staged; bv drained
#pragma unroll
        for (int kk2 = 0; kk2 < 2; kk2++) {
            v8s ap[4];
#pragma unroll
            for (int m = 0; m < 4; m++)
                ap[m] = *(const v8s*)(&Ps[cur][(m * 16 + l15) * 72 + kk2 * 32 +
                                               quad * 8]);
            v8s bva = kk2 ? bv10 : bv00;
            v8s bvb = kk2 ? bv11 : bv01;
#pragma unroll
            for (int m = 0; m < 4; m++) {
                oacc[m][0] = __builtin_amdgcn_mfma_f32_16x16x32_bf16(
                    ap[m], bva, oacc[m][0], 0, 0, 0);
                oacc[m][1] = __builtin_amdgcn_mfma_f32_16x16x32_bf16(
                    ap[m], bvb, oacc[m][1], 0, 0, 0);
            }
        }
        cur ^= 1;
    }
#pragma unroll
    for (int j = 0; j < 16; j++) {
        float s = sum16[j];
        s += __shfl_xor(s, 1);
        s += __shfl_xor(s, 2);
        s += __shfl_xor(s, 4);
        s += __shfl_xor(s, 8);
        sum16[j] = s;
    }
    if (l15 == 0) {
#pragma unroll
        for (int i = 0; i < 4; i++)
#pragma unroll
            for (int r2 = 0; r2 < 4; r2++)
                sred[w * 64 + i * 16 + quad * 4 + r2] = sum16[i * 4 + r2];
    }
    __syncthreads();
    if (tid < 64)
        sinv[tid] =
            1.f / (sred[tid] + sred[64 + tid] + sred[128 + tid] + sred[192 + tid]);
    __syncthreads();
#pragma unroll
    for (int m = 0; m < 4; m++)
#pragma unroll
        for (int r2 = 0; r2 < 4; r2++) {
            float inv = sinv[m * 16 + quad * 4 + r2];
            int row = qt * 64 + m * 16 + quad * 4 + r2;
#pragma unroll
            for (int nbi = 0; nbi < 2; nbi++) {
                int d = h * HDn + (2 * w + nbi) * 16 + l15;
                O[((size_t)b * Tn + row) * Cn + d] = oacc[m][nbi][r2] * inv;
            }
        }
}

extern "C" void kernel_launch(void* const* d_in, const int* in_sizes, int n_in,
                              void* d_out, int out_size, void* d_ws,
                              size_t ws_size, hipStream_t stream) {
    const float* hidden = (const float*)d_in[0];
    const int* mask = (const int*)d_in[1];
    const float* wq = (const float*)d_in[2];
    const float* wk = (const float*)d_in[3];
    const float* wv = (const float*)d_in[4];
    const float* wo = (const float*)d_in[5];
    const float* qg = (const float*)d_in[6];
    const float* kg = (const float*)d_in[7];
    const float* cs = (const float*)d_in[8];
    const float* sn = (const float*)d_in[9];

    char* ws = (char*)d_ws;
    int8_t* q8 = (int8_t*)(ws);                  // 24 MiB: wq,wk,wv,wo + hidden
    float* sAll = (float*)(ws + 25165824);       // 12288 fp32 scales
    u16* qb = (u16*)(ws + 25214976);             // Q bf16 (B,T,C)
    u16* kb = (u16*)(ws + 41992192);             // K bf16
    u16* vb = (u16*)(ws + 58769408);             // V bf16
    u16* vt = (u16*)(ws + 75546624);             // V^T bf16 (B,H,HD,T)
    float* Obuf = (float*)(ws + 92323840);       // O fp32 (B,T,C)
    int8_t* hid8 = q8 + 16777216;                // hidden int8 (reused for O)
    float* sx = sAll + 8192;                     // hidden scales (reused for O)

    quant_all<<<12288, 256, 0, stream>>>(wq, wk, wv, wo, hidden, q8, sAll);

    gemm_i8<<<dim3(16, 16, 3), 512, 0, stream>>>(hid8, q8, sx, sAll, (void*)qb,
                                                 4194304LL, 2048LL, 8388608LL, 0);

    norm_rope2<<<8192, 256, 0, stream>>>(qb, kb, qg, kg, cs, sn);
    vtrans<<<dim3(32, 32), 256, 0, stream>>>(vb, vt);

    flash<<<dim3(1024), 256, 0, stream>>>(qb, kb, vt, mask, Obuf);

    quant_rows<<<4096, 256, 0, stream>>>(Obuf, hid8, sx);
    gemm_i8<<<dim3(16, 16, 1), 512, 0, stream>>>(hid8, q8 + 12582912, sx,
                                                 sAll + 6144, d_out, 0LL, 0LL,
                                                 0LL, 1);
}

// Round 8
// 342.440 us; speedup vs baseline: 1.2424x; 1.0559x over previous
//
#include <hip/hip_runtime.h>
#include <stdint.h>

typedef unsigned short u16;
typedef unsigned int u32;
typedef int v4i __attribute__((ext_vector_type(4)));
typedef float v4f __attribute__((ext_vector_type(4)));
typedef short v8s __attribute__((ext_vector_type(8)));

#define Bn 2
#define Tn 2048
#define Cn 2048
#define Hn 16
#define HDn 128

__device__ __forceinline__ float b2f(u16 u) {
    u32 x = ((u32)u) << 16;
    float f;
    __builtin_memcpy(&f, &x, 4);
    return f;
}
__device__ __forceinline__ u16 f2b(float f) {
    u32 x;
    __builtin_memcpy(&x, &f, 4);
    u32 r = (x + 0x7fffu + ((x >> 16) & 1u)) >> 16;
    return (u16)r;
}

__device__ __forceinline__ void async16(const void* g, void* l) {
    __builtin_amdgcn_global_load_lds(
        (const __attribute__((address_space(1))) u32*)g,
        (__attribute__((address_space(3))) u32*)l, 16, 0, 0);
}

// ---------- fused row quantization: 4 weight matrices + hidden ----------
__global__ __launch_bounds__(256) void quant_all(
    const float* __restrict__ w0, const float* __restrict__ w1,
    const float* __restrict__ w2, const float* __restrict__ w3,
    const float* __restrict__ hid, int8_t* __restrict__ Q,
    float* __restrict__ S) {
    int r = blockIdx.x;
    const float* src;
    int ro;
    if (r < 2048) { src = w0; ro = r; }
    else if (r < 4096) { src = w1; ro = r - 2048; }
    else if (r < 6144) { src = w2; ro = r - 4096; }
    else if (r < 8192) { src = w3; ro = r - 6144; }
    else { src = hid; ro = r - 8192; }
    const float* x = src + (size_t)ro * Cn;
    int tid = threadIdx.x;
    float4 v0 = ((const float4*)x)[tid * 2];
    float4 v1 = ((const float4*)x)[tid * 2 + 1];
    float a[8] = {v0.x, v0.y, v0.z, v0.w, v1.x, v1.y, v1.z, v1.w};
    float m = 0.f;
#pragma unroll
    for (int i = 0; i < 8; i++) m = fmaxf(m, fabsf(a[i]));
#pragma unroll
    for (int o = 32; o; o >>= 1) m = fmaxf(m, __shfl_xor(m, o));
    __shared__ float sm[4];
    if ((tid & 63) == 0) sm[tid >> 6] = m;
    __syncthreads();
    m = fmaxf(fmaxf(sm[0], sm[1]), fmaxf(sm[2], sm[3]));
    float s = m * (1.0f / 127.0f) + 1e-8f;
    if (tid == 0) S[r] = s;
    u32 lo = 0, hi = 0;
#pragma unroll
    for (int i = 0; i < 8; i++) {
        float q = rintf(fminf(127.f, fmaxf(-127.f, a[i] / s)));
        int qi = (int)q;
        u32 byte = (u32)(qi & 0xff);
        if (i < 4) lo |= byte << (8 * i);
        else hi |= byte << (8 * (i - 4));
    }
    u32* qp = (u32*)(Q + (size_t)r * Cn);
    qp[tid * 2] = lo;
    qp[tid * 2 + 1] = hi;
}

// ---------- row quantization (fp32, attention output O) ----------
__global__ __launch_bounds__(256) void quant_rows(const float* __restrict__ X,
                                                  int8_t* __restrict__ Q,
                                                  float* __restrict__ S) {
    int r = blockIdx.x;
    const float* x = X + (size_t)r * Cn;
    int tid = threadIdx.x;
    float4 v0 = ((const float4*)x)[tid * 2];
    float4 v1 = ((const float4*)x)[tid * 2 + 1];
    float a[8] = {v0.x, v0.y, v0.z, v0.w, v1.x, v1.y, v1.z, v1.w};
    float m = 0.f;
#pragma unroll
    for (int i = 0; i < 8; i++) m = fmaxf(m, fabsf(a[i]));
#pragma unroll
    for (int o = 32; o; o >>= 1) m = fmaxf(m, __shfl_xor(m, o));
    __shared__ float sm[4];
    if ((tid & 63) == 0) sm[tid >> 6] = m;
    __syncthreads();
    m = fmaxf(fmaxf(sm[0], sm[1]), fmaxf(sm[2], sm[3]));
    float s = m * (1.0f / 127.0f) + 1e-8f;
    if (tid == 0) S[r] = s;
    u32 lo = 0, hi = 0;
#pragma unroll
    for (int i = 0; i < 8; i++) {
        float q = rintf(fminf(127.f, fmaxf(-127.f, a[i] / s)));
        int qi = (int)q;
        u32 byte = (u32)(qi & 0xff);
        if (i < 4) lo |= byte << (8 * i);
        else hi |= byte << (8 * (i - 4));
    }
    u32* qp = (u32*)(Q + (size_t)r * Cn);
    qp[tid * 2] = lo;
    qp[tid * 2 + 1] = hi;
}

// ---------- int8 GEMM (R4 single-buffer 128^2, proven fastest config).
// NEW: z==2 (V projection) writes its output DIRECTLY TRANSPOSED into
// Vt[bh][d][t] from the epilogue (4 consecutive t per thread = one 8B
// ushort4 store) -> vtrans kernel + 32MB of V round-trip eliminated. ----------
__global__ __launch_bounds__(256) void gemm_i8(
    const int8_t* __restrict__ A, const int8_t* __restrict__ Bw,
    const float* __restrict__ sA, const float* __restrict__ sB,
    void* __restrict__ Co, long long bStride, long long sbStride,
    long long cStride, int fp32out, u16* __restrict__ vtOut) {
    int z = blockIdx.z;
    Bw += (size_t)z * bStride;
    sB += (size_t)z * sbStride;
    const int K = 2048, N = 2048;
    __shared__ int8_t As[128 * 64];
    __shared__ int8_t Bs[128 * 64];
    int m0 = blockIdx.x * 128, n0 = blockIdx.y * 128;
    int tid = threadIdx.x, w = tid >> 6, lane = tid & 63;
    int quad = lane >> 4, l15 = lane & 15;
    int wy = w >> 1, wx = w & 1;
    const v4i zi = {0, 0, 0, 0};
    v4i acc[4][4];
#pragma unroll
    for (int i = 0; i < 4; i++)
#pragma unroll
        for (int j = 0; j < 4; j++) acc[i][j] = zi;
    int lrow = lane >> 2;
    int slot = lane & 3;
    int srow = w * 32 + lrow;
    int klog = ((slot ^ (lrow & 3)) * 16);
    const int8_t* ga = A + (size_t)(m0 + srow) * K + klog;
    const int8_t* gb = Bw + (size_t)(n0 + srow) * K + klog;
    int8_t* la = &As[srow * 64 + slot * 16];
    int8_t* lb = &Bs[srow * 64 + slot * 16];
    for (int k0 = 0; k0 < K; k0 += 64) {
        async16(ga + k0, la);
        async16(ga + k0 + (size_t)16 * K, la + 16 * 64);
        async16(gb + k0, lb);
        async16(gb + k0 + (size_t)16 * K, lb + 16 * 64);
        __syncthreads();
        int swz = (quad ^ (l15 & 3)) * 16;
        v4i af[4], bf4[4];
#pragma unroll
        for (int i = 0; i < 4; i++)
            af[i] = *(const v4i*)&As[(wy * 64 + i * 16 + l15) * 64 + swz];
#pragma unroll
        for (int j = 0; j < 4; j++)
            bf4[j] = *(const v4i*)&Bs[(wx * 64 + j * 16 + l15) * 64 + swz];
#pragma unroll
        for (int i = 0; i < 4; i++)
#pragma unroll
            for (int j = 0; j < 4; j++)
                acc[i][j] = __builtin_amdgcn_mfma_i32_16x16x64_i8(
                    af[i], bf4[j], acc[i][j], 0, 0, 0);
        __syncthreads();
    }
    bool vmode = (z == 2) && (vtOut != nullptr);
#pragma unroll
    for (int i = 0; i < 4; i++) {
        int mb = m0 + wy * 64 + i * 16 + quad * 4;
        float s0 = sA[mb], s1 = sA[mb + 1], s2 = sA[mb + 2], s3 = sA[mb + 3];
#pragma unroll
        for (int j = 0; j < 4; j++) {
            int n = n0 + wx * 64 + j * 16 + l15;
            float sb = sB[n];
            if (fp32out) {
                float* cp = (float*)Co + (size_t)cStride * z + (size_t)mb * N + n;
                cp[0] = (float)acc[i][j][0] * s0 * sb;
                cp[N] = (float)acc[i][j][1] * s1 * sb;
                cp[2 * N] = (float)acc[i][j][2] * s2 * sb;
                cp[3 * N] = (float)acc[i][j][3] * s3 * sb;
            } else if (vmode) {
                // V element (b,t,h,d): row mb = b*2048+t, col n = h*128+d.
                // Vt[bh][d][t]; 4 acc rows = t..t+3 (t%4==0) -> one 8B store.
                int bidx = mb >> 11, t = mb & 2047;
                int hh = n >> 7, d = n & 127;
                u16* vp =
                    vtOut + (((size_t)(bidx * 16 + hh) * 128 + d) * 2048 + t);
                ushort4 pk;
                pk.x = f2b((float)acc[i][j][0] * s0 * sb);
                pk.y = f2b((float)acc[i][j][1] * s1 * sb);
                pk.z = f2b((float)acc[i][j][2] * s2 * sb);
                pk.w = f2b((float)acc[i][j][3] * s3 * sb);
                *(ushort4*)vp = pk;
            } else {
                u16* cp = (u16*)Co + (size_t)cStride * z + (size_t)mb * N + n;
                cp[0] = f2b((float)acc[i][j][0] * s0 * sb);
                cp[N] = f2b((float)acc[i][j][1] * s1 * sb);
                cp[2 * N] = f2b((float)acc[i][j][2] * s2 * sb);
                cp[3 * N] = f2b((float)acc[i][j][3] * s3 * sb);
            }
        }
    }
}

// ---------- fused RMSNorm + RoPE (Q gets 1/sqrt(HD) folded) ----------
__global__ __launch_bounds__(256) void norm_rope2(u16* __restrict__ Qb,
                                                  u16* __restrict__ Kb,
                                                  const float* __restrict__ qg,
                                                  const float* __restrict__ kg,
                                                  const float* __restrict__ cs,
                                                  const float* __restrict__ sn) {
    int row = blockIdx.x;
    int isq = row < 4096;
    row &= 4095;
    u16* x = (isq ? Qb : Kb) + (size_t)row * Cn;
    const float* g = isq ? qg : kg;
    float ps = isq ? 0.08838834764831845f : 1.0f;
    int t = row & (Tn - 1);
    int tid = threadIdx.x;
    uint4 raw = ((const uint4*)x)[tid];
    u16 us[8];
    us[0] = raw.x & 0xffff; us[1] = raw.x >> 16;
    us[2] = raw.y & 0xffff; us[3] = raw.y >> 16;
    us[4] = raw.z & 0xffff; us[5] = raw.z >> 16;
    us[6] = raw.w & 0xffff; us[7] = raw.w >> 16;
    float v[8];
#pragma unroll
    for (int i = 0; i < 8; i++) v[i] = b2f(us[i]);
    float ss = 0.f;
#pragma unroll
    for (int i = 0; i < 8; i++) ss += v[i] * v[i];
#pragma unroll
    for (int o = 32; o; o >>= 1) ss += __shfl_xor(ss, o);
    __shared__ float sm[4];
    if ((tid & 63) == 0) sm[tid >> 6] = ss;
    __syncthreads();
    ss = sm[0] + sm[1] + sm[2] + sm[3];
    float r = rsqrtf(ss * (1.f / 2048.f) + 1e-6f) * ps;
    float4 g0 = ((const float4*)g)[tid * 2];
    float4 g1 = ((const float4*)g)[tid * 2 + 1];
    float n[8];
    n[0] = v[0] * r * g0.x; n[1] = v[1] * r * g0.y;
    n[2] = v[2] * r * g0.z; n[3] = v[3] * r * g0.w;
    n[4] = v[4] * r * g1.x; n[5] = v[5] * r * g1.y;
    n[6] = v[6] * r * g1.z; n[7] = v[7] * r * g1.w;
    int pi = (tid & 15) * 4;
    float4 c4 = *(const float4*)(cs + t * 64 + pi);
    float4 s4 = *(const float4*)(sn + t * 64 + pi);
    float o[8];
    o[0] = n[0] * c4.x - n[1] * s4.x; o[1] = n[0] * s4.x + n[1] * c4.x;
    o[2] = n[2] * c4.y - n[3] * s4.y; o[3] = n[2] * s4.y + n[3] * c4.y;
    o[4] = n[4] * c4.z - n[5] * s4.z; o[5] = n[4] * s4.z + n[5] * c4.z;
    o[6] = n[6] * c4.w - n[7] * s4.w; o[7] = n[6] * s4.w + n[7] * c4.w;
    uint4 out;
    out.x = (u32)f2b(o[0]) | ((u32)f2b(o[1]) << 16);
    out.y = (u32)f2b(o[2]) | ((u32)f2b(o[3]) << 16);
    out.z = (u32)f2b(o[4]) | ((u32)f2b(o[5]) << 16);
    out.w = (u32)f2b(o[6]) | ((u32)f2b(o[7]) << 16);
    ((uint4*)x)[tid] = out;
}

// ---------- flash v7 (exact R5 best, 82.8us: K dbuf + V->reg post-barrier
// + XCD swizzle, __expf) ----------
__global__ __launch_bounds__(256, 3) void flash(const u16* __restrict__ Qb,
                                                const u16* __restrict__ Kb,
                                                const u16* __restrict__ Vt,
                                                const int* __restrict__ mask,
                                                float* __restrict__ O) {
    int id = blockIdx.x;
    int bh = (id & 7) + 8 * (id >> 8);  // XCD-aware (proven: FETCH 93->21MB)
    int qt = (id >> 3) & 31;
    int b = bh >> 4, h = bh & 15;
    int L = mask[b];
    int nkfull = L >> 6;
    int nk = (L + 63) >> 6;
    __shared__ u16 Ks[2][64 * 128];
    __shared__ u16 Ps[2][64 * 72];
    __shared__ float sred[256];
    __shared__ float sinv[64];
    int tid = threadIdx.x, w = tid >> 6, lane = tid & 63;
    int quad = lane >> 4, l15 = lane & 15;

    v8s aq[4][4];
#pragma unroll
    for (int i = 0; i < 4; i++)
#pragma unroll
        for (int kk = 0; kk < 4; kk++)
            aq[i][kk] = *(const v8s*)(Qb +
                                      ((size_t)b * Tn + qt * 64 + i * 16 + l15) * Cn +
                                      h * HDn + kk * 32 + quad * 8);

    const u16* ksp[4];
    int kdo[4];
#pragma unroll
    for (int cc = 0; cc < 4; cc++) {
        int c = w * 4 + cc;
        int rk = c * 4 + (lane >> 4);
        int sk = lane & 15;
        int lgk = sk ^ (rk & 7);
        ksp[cc] = Kb + ((size_t)b * Tn + rk) * Cn + h * HDn + lgk * 8;
        kdo[cc] = rk * 128 + sk * 8;
    }

    const u16* vp0 = Vt + ((size_t)bh * HDn + 2 * w * 16 + l15) * Tn + quad * 8;
    const u16* vp1 = vp0 + 16 * Tn;

    float sum16[16];
#pragma unroll
    for (int j = 0; j < 16; j++) sum16[j] = 0.f;
    const v4f zf = {0.f, 0.f, 0.f, 0.f};
    v4f oacc[4][2];
#pragma unroll
    for (int m = 0; m < 4; m++) {
        oacc[m][0] = zf;
        oacc[m][1] = zf;
    }

#pragma unroll
    for (int cc = 0; cc < 4; cc++) {
        async16(ksp[cc], &Ks[0][kdo[cc]]);
        ksp[cc] += (size_t)64 * Cn;
    }
    __syncthreads();

    int cur = 0;
    for (int kt = 0; kt < nk; kt++) {
        if (kt + 1 < nk) {
#pragma unroll
            for (int cc = 0; cc < 4; cc++) {
                async16(ksp[cc], &Ks[cur ^ 1][kdo[cc]]);
                ksp[cc] += (size_t)64 * Cn;
            }
        }
        v8s bv00 = *(const v8s*)(vp0);
        v8s bv10 = *(const v8s*)(vp0 + 32);
        v8s bv01 = *(const v8s*)(vp1);
        v8s bv11 = *(const v8s*)(vp1 + 32);
        vp0 += 64;
        vp1 += 64;
        v4f sacc[4] = {zf, zf, zf, zf};
        const u16* krow = &Ks[cur][(w * 16 + l15) * 128];
#pragma unroll
        for (int kk = 0; kk < 4; kk++) {
            v8s bk = *(const v8s*)(krow + ((((kk * 4 + quad) ^ (l15 & 7))) << 3));
#pragma unroll
            for (int i = 0; i < 4; i++)
                sacc[i] = __builtin_amdgcn_mfma_f32_16x16x32_bf16(aq[i][kk], bk,
                                                                  sacc[i], 0, 0, 0);
        }
        bool valid = (kt < nkfull) || ((kt * 64 + w * 16 + l15) < L);
#pragma unroll
        for (int i = 0; i < 4; i++)
#pragma unroll
            for (int r2 = 0; r2 < 4; r2++) {
                float p = valid ? __expf(sacc[i][r2]) : 0.f;
                sum16[i * 4 + r2] += p;
                Ps[cur][(i * 16 + quad * 4 + r2) * 72 + w * 16 + l15] = f2b(p);
            }
        __syncthreads();  // Ps[cur] visible; K(kt+1) staged; bv drained
#pragma unroll
        for (int kk2 = 0; kk2 < 2; kk2++) {
            v8s ap[4];
#pragma unroll
            for (int m = 0; m < 4; m++)
                ap[m] = *(const v8s*)(&Ps[cur][(m * 16 + l15) * 72 + kk2 * 32 +
                                               quad * 8]);
            v8s bva = kk2 ? bv10 : bv00;
            v8s bvb = kk2 ? bv11 : bv01;
#pragma unroll
            for (int m = 0; m < 4; m++) {
                oacc[m][0] = __builtin_amdgcn_mfma_f32_16x16x32_bf16(
                    ap[m], bva, oacc[m][0], 0, 0, 0);
                oacc[m][1] = __builtin_amdgcn_mfma_f32_16x16x32_bf16(
                    ap[m], bvb, oacc[m][1], 0, 0, 0);
            }
        }
        cur ^= 1;
    }
#pragma unroll
    for (int j = 0; j < 16; j++) {
        float s = sum16[j];
        s += __shfl_xor(s, 1);
        s += __shfl_xor(s, 2);
        s += __shfl_xor(s, 4);
        s += __shfl_xor(s, 8);
        sum16[j] = s;
    }
    if (l15 == 0) {
#pragma unroll
        for (int i = 0; i < 4; i++)
#pragma unroll
            for (int r2 = 0; r2 < 4; r2++)
                sred[w * 64 + i * 16 + quad * 4 + r2] = sum16[i * 4 + r2];
    }
    __syncthreads();
    if (tid < 64)
        sinv[tid] =
            1.f / (sred[tid] + sred[64 + tid] + sred[128 + tid] + sred[192 + tid]);
    __syncthreads();
#pragma unroll
    for (int m = 0; m < 4; m++)
#pragma unroll
        for (int r2 = 0; r2 < 4; r2++) {
            float inv = sinv[m * 16 + quad * 4 + r2];
            int row = qt * 64 + m * 16 + quad * 4 + r2;
#pragma unroll
            for (int nbi = 0; nbi < 2; nbi++) {
                int d = h * HDn + (2 * w + nbi) * 16 + l15;
                O[((size_t)b * Tn + row) * Cn + d] = oacc[m][nbi][r2] * inv;
            }
        }
}

extern "C" void kernel_launch(void* const* d_in, const int* in_sizes, int n_in,
                              void* d_out, int out_size, void* d_ws,
                              size_t ws_size, hipStream_t stream) {
    const float* hidden = (const float*)d_in[0];
    const int* mask = (const int*)d_in[1];
    const float* wq = (const float*)d_in[2];
    const float* wk = (const float*)d_in[3];
    const float* wv = (const float*)d_in[4];
    const float* wo = (const float*)d_in[5];
    const float* qg = (const float*)d_in[6];
    const float* kg = (const float*)d_in[7];
    const float* cs = (const float*)d_in[8];
    const float* sn = (const float*)d_in[9];

    char* ws = (char*)d_ws;
    int8_t* q8 = (int8_t*)(ws);                  // 24 MiB: wq,wk,wv,wo + hidden
    float* sAll = (float*)(ws + 25165824);       // 12288 fp32 scales
    u16* qb = (u16*)(ws + 25214976);             // Q bf16 (B,T,C)
    u16* kb = (u16*)(ws + 41992192);             // K bf16
    u16* vt = (u16*)(ws + 75546624);             // V^T bf16 (B,H,HD,T)
    float* Obuf = (float*)(ws + 92323840);       // O fp32 (B,T,C)
    int8_t* hid8 = q8 + 16777216;                // hidden int8 (reused for O)
    float* sx = sAll + 8192;                     // hidden scales (reused for O)

    quant_all<<<12288, 256, 0, stream>>>(wq, wk, wv, wo, hidden, q8, sAll);

    // z=0 -> Q bf16 (qb), z=1 -> K bf16 (kb), z=2 -> V written TRANSPOSED to vt
    gemm_i8<<<dim3(32, 16, 3), 256, 0, stream>>>(hid8, q8, sx, sAll, (void*)qb,
                                                 4194304LL, 2048LL, 8388608LL, 0,
                                                 vt);

    norm_rope2<<<8192, 256, 0, stream>>>(qb, kb, qg, kg, cs, sn);

    flash<<<dim3(1024), 256, 0, stream>>>(qb, kb, vt, mask, Obuf);

    quant_rows<<<4096, 256, 0, stream>>>(Obuf, hid8, sx);
    gemm_i8<<<dim3(32, 16, 1), 256, 0, stream>>>(hid8, q8 + 12582912, sx,
                                                 sAll + 6144, d_out, 0LL, 0LL,
                                                 0LL, 1, nullptr);
}

// Round 9
// 338.159 us; speedup vs baseline: 1.2581x; 1.0127x over previous
//
#include <hip/hip_runtime.h>
#include <stdint.h>

typedef unsigned short u16;
typedef unsigned int u32;
typedef int v4i __attribute__((ext_vector_type(4)));
typedef float v4f __attribute__((ext_vector_type(4)));
typedef short v8s __attribute__((ext_vector_type(8)));

#define Bn 2
#define Tn 2048
#define Cn 2048
#define Hn 16
#define HDn 128

__device__ __forceinline__ float b2f(u16 u) {
    u32 x = ((u32)u) << 16;
    float f;
    __builtin_memcpy(&f, &x, 4);
    return f;
}
__device__ __forceinline__ u16 f2b(float f) {
    u32 x;
    __builtin_memcpy(&x, &f, 4);
    u32 r = (x + 0x7fffu + ((x >> 16) & 1u)) >> 16;
    return (u16)r;
}

__device__ __forceinline__ void async16(const void* g, void* l) {
    __builtin_amdgcn_global_load_lds(
        (const __attribute__((address_space(1))) u32*)g,
        (__attribute__((address_space(3))) u32*)l, 16, 0, 0);
}

// ---------- fused row quantization: 4 weight matrices + hidden ----------
__global__ __launch_bounds__(256) void quant_all(
    const float* __restrict__ w0, const float* __restrict__ w1,
    const float* __restrict__ w2, const float* __restrict__ w3,
    const float* __restrict__ hid, int8_t* __restrict__ Q,
    float* __restrict__ S) {
    int r = blockIdx.x;
    const float* src;
    int ro;
    if (r < 2048) { src = w0; ro = r; }
    else if (r < 4096) { src = w1; ro = r - 2048; }
    else if (r < 6144) { src = w2; ro = r - 4096; }
    else if (r < 8192) { src = w3; ro = r - 6144; }
    else { src = hid; ro = r - 8192; }
    const float* x = src + (size_t)ro * Cn;
    int tid = threadIdx.x;
    float4 v0 = ((const float4*)x)[tid * 2];
    float4 v1 = ((const float4*)x)[tid * 2 + 1];
    float a[8] = {v0.x, v0.y, v0.z, v0.w, v1.x, v1.y, v1.z, v1.w};
    float m = 0.f;
#pragma unroll
    for (int i = 0; i < 8; i++) m = fmaxf(m, fabsf(a[i]));
#pragma unroll
    for (int o = 32; o; o >>= 1) m = fmaxf(m, __shfl_xor(m, o));
    __shared__ float sm[4];
    if ((tid & 63) == 0) sm[tid >> 6] = m;
    __syncthreads();
    m = fmaxf(fmaxf(sm[0], sm[1]), fmaxf(sm[2], sm[3]));
    float s = m * (1.0f / 127.0f) + 1e-8f;
    if (tid == 0) S[r] = s;
    u32 lo = 0, hi = 0;
#pragma unroll
    for (int i = 0; i < 8; i++) {
        float q = rintf(fminf(127.f, fmaxf(-127.f, a[i] / s)));
        int qi = (int)q;
        u32 byte = (u32)(qi & 0xff);
        if (i < 4) lo |= byte << (8 * i);
        else hi |= byte << (8 * (i - 4));
    }
    u32* qp = (u32*)(Q + (size_t)r * Cn);
    qp[tid * 2] = lo;
    qp[tid * 2 + 1] = hi;
}

// ---------- row quantization (fp32, attention output O) ----------
__global__ __launch_bounds__(256) void quant_rows(const float* __restrict__ X,
                                                  int8_t* __restrict__ Q,
                                                  float* __restrict__ S) {
    int r = blockIdx.x;
    const float* x = X + (size_t)r * Cn;
    int tid = threadIdx.x;
    float4 v0 = ((const float4*)x)[tid * 2];
    float4 v1 = ((const float4*)x)[tid * 2 + 1];
    float a[8] = {v0.x, v0.y, v0.z, v0.w, v1.x, v1.y, v1.z, v1.w};
    float m = 0.f;
#pragma unroll
    for (int i = 0; i < 8; i++) m = fmaxf(m, fabsf(a[i]));
#pragma unroll
    for (int o = 32; o; o >>= 1) m = fmaxf(m, __shfl_xor(m, o));
    __shared__ float sm[4];
    if ((tid & 63) == 0) sm[tid >> 6] = m;
    __syncthreads();
    m = fmaxf(fmaxf(sm[0], sm[1]), fmaxf(sm[2], sm[3]));
    float s = m * (1.0f / 127.0f) + 1e-8f;
    if (tid == 0) S[r] = s;
    u32 lo = 0, hi = 0;
#pragma unroll
    for (int i = 0; i < 8; i++) {
        float q = rintf(fminf(127.f, fmaxf(-127.f, a[i] / s)));
        int qi = (int)q;
        u32 byte = (u32)(qi & 0xff);
        if (i < 4) lo |= byte << (8 * i);
        else hi |= byte << (8 * (i - 4));
    }
    u32* qp = (u32*)(Q + (size_t)r * Cn);
    qp[tid * 2] = lo;
    qp[tid * 2 + 1] = hi;
}

// ---------- int8 GEMM (R4 single-buffer core; R8 fused V-transpose epilogue).
// NEW (R9): XCD-chunked block mapping. wg&7 selects the XCD (linear dispatch
// round-robins %8, verified on flash: FETCH 93->21MB). XCD owns an 8x8-block
// (m,n) quadrant: A 8x256KB + B 8x256KB = 4MB = exactly one L2. Bijective:
// xcd=(m/8)*2+(n/8), c=(m%8)*8+(n%8). Sync structure untouched. ----------
__global__ __launch_bounds__(256) void gemm_i8(
    const int8_t* __restrict__ A, const int8_t* __restrict__ Bw,
    const float* __restrict__ sA, const float* __restrict__ sB,
    void* __restrict__ Co, long long bStride, long long sbStride,
    long long cStride, int fp32out, u16* __restrict__ vtOut) {
    int wg = blockIdx.x, z = blockIdx.y;
    Bw += (size_t)z * bStride;
    sB += (size_t)z * sbStride;
    const int K = 2048, N = 2048;
    __shared__ int8_t As[128 * 64];
    __shared__ int8_t Bs[128 * 64];
    int xcd = wg & 7, c = wg >> 3;
    int m0 = ((xcd >> 1) * 8 + (c >> 3)) * 128;
    int n0 = ((xcd & 1) * 8 + (c & 7)) * 128;
    int tid = threadIdx.x, w = tid >> 6, lane = tid & 63;
    int quad = lane >> 4, l15 = lane & 15;
    int wy = w >> 1, wx = w & 1;
    const v4i zi = {0, 0, 0, 0};
    v4i acc[4][4];
#pragma unroll
    for (int i = 0; i < 4; i++)
#pragma unroll
        for (int j = 0; j < 4; j++) acc[i][j] = zi;
    int lrow = lane >> 2;
    int slot = lane & 3;
    int srow = w * 32 + lrow;
    int klog = ((slot ^ (lrow & 3)) * 16);
    const int8_t* ga = A + (size_t)(m0 + srow) * K + klog;
    const int8_t* gb = Bw + (size_t)(n0 + srow) * K + klog;
    int8_t* la = &As[srow * 64 + slot * 16];
    int8_t* lb = &Bs[srow * 64 + slot * 16];
    for (int k0 = 0; k0 < K; k0 += 64) {
        async16(ga + k0, la);
        async16(ga + k0 + (size_t)16 * K, la + 16 * 64);
        async16(gb + k0, lb);
        async16(gb + k0 + (size_t)16 * K, lb + 16 * 64);
        __syncthreads();
        int swz = (quad ^ (l15 & 3)) * 16;
        v4i af[4], bf4[4];
#pragma unroll
        for (int i = 0; i < 4; i++)
            af[i] = *(const v4i*)&As[(wy * 64 + i * 16 + l15) * 64 + swz];
#pragma unroll
        for (int j = 0; j < 4; j++)
            bf4[j] = *(const v4i*)&Bs[(wx * 64 + j * 16 + l15) * 64 + swz];
#pragma unroll
        for (int i = 0; i < 4; i++)
#pragma unroll
            for (int j = 0; j < 4; j++)
                acc[i][j] = __builtin_amdgcn_mfma_i32_16x16x64_i8(
                    af[i], bf4[j], acc[i][j], 0, 0, 0);
        __syncthreads();
    }
    bool vmode = (z == 2) && (vtOut != nullptr);
#pragma unroll
    for (int i = 0; i < 4; i++) {
        int mb = m0 + wy * 64 + i * 16 + quad * 4;
        float s0 = sA[mb], s1 = sA[mb + 1], s2 = sA[mb + 2], s3 = sA[mb + 3];
#pragma unroll
        for (int j = 0; j < 4; j++) {
            int n = n0 + wx * 64 + j * 16 + l15;
            float sb = sB[n];
            if (fp32out) {
                float* cp = (float*)Co + (size_t)cStride * z + (size_t)mb * N + n;
                cp[0] = (float)acc[i][j][0] * s0 * sb;
                cp[N] = (float)acc[i][j][1] * s1 * sb;
                cp[2 * N] = (float)acc[i][j][2] * s2 * sb;
                cp[3 * N] = (float)acc[i][j][3] * s3 * sb;
            } else if (vmode) {
                // V element (b,t,h,d): row mb = b*2048+t, col n = h*128+d.
                // Vt[bh][d][t]; 4 acc rows = t..t+3 (t%4==0) -> one 8B store.
                int bidx = mb >> 11, t = mb & 2047;
                int hh = n >> 7, d = n & 127;
                u16* vp =
                    vtOut + (((size_t)(bidx * 16 + hh) * 128 + d) * 2048 + t);
                ushort4 pk;
                pk.x = f2b((float)acc[i][j][0] * s0 * sb);
                pk.y = f2b((float)acc[i][j][1] * s1 * sb);
                pk.z = f2b((float)acc[i][j][2] * s2 * sb);
                pk.w = f2b((float)acc[i][j][3] * s3 * sb);
                *(ushort4*)vp = pk;
            } else {
                u16* cp = (u16*)Co + (size_t)cStride * z + (size_t)mb * N + n;
                cp[0] = f2b((float)acc[i][j][0] * s0 * sb);
                cp[N] = f2b((float)acc[i][j][1] * s1 * sb);
                cp[2 * N] = f2b((float)acc[i][j][2] * s2 * sb);
                cp[3 * N] = f2b((float)acc[i][j][3] * s3 * sb);
            }
        }
    }
}

// ---------- fused RMSNorm + RoPE (Q gets 1/sqrt(HD) folded) ----------
__global__ __launch_bounds__(256) void norm_rope2(u16* __restrict__ Qb,
                                                  u16* __restrict__ Kb,
                                                  const float* __restrict__ qg,
                                                  const float* __restrict__ kg,
                                                  const float* __restrict__ cs,
                                                  const float* __restrict__ sn) {
    int row = blockIdx.x;
    int isq = row < 4096;
    row &= 4095;
    u16* x = (isq ? Qb : Kb) + (size_t)row * Cn;
    const float* g = isq ? qg : kg;
    float ps = isq ? 0.08838834764831845f : 1.0f;
    int t = row & (Tn - 1);
    int tid = threadIdx.x;
    uint4 raw = ((const uint4*)x)[tid];
    u16 us[8];
    us[0] = raw.x & 0xffff; us[1] = raw.x >> 16;
    us[2] = raw.y & 0xffff; us[3] = raw.y >> 16;
    us[4] = raw.z & 0xffff; us[5] = raw.z >> 16;
    us[6] = raw.w & 0xffff; us[7] = raw.w >> 16;
    float v[8];
#pragma unroll
    for (int i = 0; i < 8; i++) v[i] = b2f(us[i]);
    float ss = 0.f;
#pragma unroll
    for (int i = 0; i < 8; i++) ss += v[i] * v[i];
#pragma unroll
    for (int o = 32; o; o >>= 1) ss += __shfl_xor(ss, o);
    __shared__ float sm[4];
    if ((tid & 63) == 0) sm[tid >> 6] = ss;
    __syncthreads();
    ss = sm[0] + sm[1] + sm[2] + sm[3];
    float r = rsqrtf(ss * (1.f / 2048.f) + 1e-6f) * ps;
    float4 g0 = ((const float4*)g)[tid * 2];
    float4 g1 = ((const float4*)g)[tid * 2 + 1];
    float n[8];
    n[0] = v[0] * r * g0.x; n[1] = v[1] * r * g0.y;
    n[2] = v[2] * r * g0.z; n[3] = v[3] * r * g0.w;
    n[4] = v[4] * r * g1.x; n[5] = v[5] * r * g1.y;
    n[6] = v[6] * r * g1.z; n[7] = v[7] * r * g1.w;
    int pi = (tid & 15) * 4;
    float4 c4 = *(const float4*)(cs + t * 64 + pi);
    float4 s4 = *(const float4*)(sn + t * 64 + pi);
    float o[8];
    o[0] = n[0] * c4.x - n[1] * s4.x; o[1] = n[0] * s4.x + n[1] * c4.x;
    o[2] = n[2] * c4.y - n[3] * s4.y; o[3] = n[2] * s4.y + n[3] * c4.y;
    o[4] = n[4] * c4.z - n[5] * s4.z; o[5] = n[4] * s4.z + n[5] * c4.z;
    o[6] = n[6] * c4.w - n[7] * s4.w; o[7] = n[6] * s4.w + n[7] * c4.w;
    uint4 out;
    out.x = (u32)f2b(o[0]) | ((u32)f2b(o[1]) << 16);
    out.y = (u32)f2b(o[2]) | ((u32)f2b(o[3]) << 16);
    out.z = (u32)f2b(o[4]) | ((u32)f2b(o[5]) << 16);
    out.w = (u32)f2b(o[6]) | ((u32)f2b(o[7]) << 16);
    ((uint4*)x)[tid] = out;
}

// ---------- flash v7 (exact R5 best, 82.0us: K dbuf + V->reg post-barrier
// + XCD swizzle, __expf) ----------
__global__ __launch_bounds__(256, 3) void flash(const u16* __restrict__ Qb,
                                                const u16* __restrict__ Kb,
                                                const u16* __restrict__ Vt,
                                                const int* __restrict__ mask,
                                                float* __restrict__ O) {
    int id = blockIdx.x;
    int bh = (id & 7) + 8 * (id >> 8);  // XCD-aware (proven: FETCH 93->21MB)
    int qt = (id >> 3) & 31;
    int b = bh >> 4, h = bh & 15;
    int L = mask[b];
    int nkfull = L >> 6;
    int nk = (L + 63) >> 6;
    __shared__ u16 Ks[2][64 * 128];
    __shared__ u16 Ps[2][64 * 72];
    __shared__ float sred[256];
    __shared__ float sinv[64];
    int tid = threadIdx.x, w = tid >> 6, lane = tid & 63;
    int quad = lane >> 4, l15 = lane & 15;

    v8s aq[4][4];
#pragma unroll
    for (int i = 0; i < 4; i++)
#pragma unroll
        for (int kk = 0; kk < 4; kk++)
            aq[i][kk] = *(const v8s*)(Qb +
                                      ((size_t)b * Tn + qt * 64 + i * 16 + l15) * Cn +
                                      h * HDn + kk * 32 + quad * 8);

    const u16* ksp[4];
    int kdo[4];
#pragma unroll
    for (int cc = 0; cc < 4; cc++) {
        int c = w * 4 + cc;
        int rk = c * 4 + (lane >> 4);
        int sk = lane & 15;
        int lgk = sk ^ (rk & 7);
        ksp[cc] = Kb + ((size_t)b * Tn + rk) * Cn + h * HDn + lgk * 8;
        kdo[cc] = rk * 128 + sk * 8;
    }

    const u16* vp0 = Vt + ((size_t)bh * HDn + 2 * w * 16 + l15) * Tn + quad * 8;
    const u16* vp1 = vp0 + 16 * Tn;

    float sum16[16];
#pragma unroll
    for (int j = 0; j < 16; j++) sum16[j] = 0.f;
    const v4f zf = {0.f, 0.f, 0.f, 0.f};
    v4f oacc[4][2];
#pragma unroll
    for (int m = 0; m < 4; m++) {
        oacc[m][0] = zf;
        oacc[m][1] = zf;
    }

#pragma unroll
    for (int cc = 0; cc < 4; cc++) {
        async16(ksp[cc], &Ks[0][kdo[cc]]);
        ksp[cc] += (size_t)64 * Cn;
    }
    __syncthreads();

    int cur = 0;
    for (int kt = 0; kt < nk; kt++) {
        if (kt + 1 < nk) {
#pragma unroll
            for (int cc = 0; cc < 4; cc++) {
                async16(ksp[cc], &Ks[cur ^ 1][kdo[cc]]);
                ksp[cc] += (size_t)64 * Cn;
            }
        }
        v8s bv00 = *(const v8s*)(vp0);
        v8s bv10 = *(const v8s*)(vp0 + 32);
        v8s bv01 = *(const v8s*)(vp1);
        v8s bv11 = *(const v8s*)(vp1 + 32);
        vp0 += 64;
        vp1 += 64;
        v4f sacc[4] = {zf, zf, zf, zf};
        const u16* krow = &Ks[cur][(w * 16 + l15) * 128];
#pragma unroll
        for (int kk = 0; kk < 4; kk++) {
            v8s bk = *(const v8s*)(krow + ((((kk * 4 + quad) ^ (l15 & 7))) << 3));
#pragma unroll
            for (int i = 0; i < 4; i++)
                sacc[i] = __builtin_amdgcn_mfma_f32_16x16x32_bf16(aq[i][kk], bk,
                                                                  sacc[i], 0, 0, 0);
        }
        bool valid = (kt < nkfull) || ((kt * 64 + w * 16 + l15) < L);
#pragma unroll
        for (int i = 0; i < 4; i++)
#pragma unroll
            for (int r2 = 0; r2 < 4; r2++) {
                float p = valid ? __expf(sacc[i][r2]) : 0.f;
                sum16[i * 4 + r2] += p;
                Ps[cur][(i * 16 + quad * 4 + r2) * 72 + w * 16 + l15] = f2b(p);
            }
        __syncthreads();  // Ps[cur] visible; K(kt+1) staged; bv drained
#pragma unroll
        for (int kk2 = 0; kk2 < 2; kk2++) {
            v8s ap[4];
#pragma unroll
            for (int m = 0; m < 4; m++)
                ap[m] = *(const v8s*)(&Ps[cur][(m * 16 + l15) * 72 + kk2 * 32 +
                                               quad * 8]);
            v8s bva = kk2 ? bv10 : bv00;
            v8s bvb = kk2 ? bv11 : bv01;
#pragma unroll
            for (int m = 0; m < 4; m++) {
                oacc[m][0] = __builtin_amdgcn_mfma_f32_16x16x32_bf16(
                    ap[m], bva, oacc[m][0], 0, 0, 0);
                oacc[m][1] = __builtin_amdgcn_mfma_f32_16x16x32_bf16(
                    ap[m], bvb, oacc[m][1], 0, 0, 0);
            }
        }
        cur ^= 1;
    }
#pragma unroll
    for (int j = 0; j < 16; j++) {
        float s = sum16[j];
        s += __shfl_xor(s, 1);
        s += __shfl_xor(s, 2);
        s += __shfl_xor(s, 4);
        s += __shfl_xor(s, 8);
        sum16[j] = s;
    }
    if (l15 == 0) {
#pragma unroll
        for (int i = 0; i < 4; i++)
#pragma unroll
            for (int r2 = 0; r2 < 4; r2++)
                sred[w * 64 + i * 16 + quad * 4 + r2] = sum16[i * 4 + r2];
    }
    __syncthreads();
    if (tid < 64)
        sinv[tid] =
            1.f / (sred[tid] + sred[64 + tid] + sred[128 + tid] + sred[192 + tid]);
    __syncthreads();
#pragma unroll
    for (int m = 0; m < 4; m++)
#pragma unroll
        for (int r2 = 0; r2 < 4; r2++) {
            float inv = sinv[m * 16 + quad * 4 + r2];
            int row = qt * 64 + m * 16 + quad * 4 + r2;
#pragma unroll
            for (int nbi = 0; nbi < 2; nbi++) {
                int d = h * HDn + (2 * w + nbi) * 16 + l15;
                O[((size_t)b * Tn + row) * Cn + d] = oacc[m][nbi][r2] * inv;
            }
        }
}

extern "C" void kernel_launch(void* const* d_in, const int* in_sizes, int n_in,
                              void* d_out, int out_size, void* d_ws,
                              size_t ws_size, hipStream_t stream) {
    const float* hidden = (const float*)d_in[0];
    const int* mask = (const int*)d_in[1];
    const float* wq = (const float*)d_in[2];
    const float* wk = (const float*)d_in[3];
    const float* wv = (const float*)d_in[4];
    const float* wo = (const float*)d_in[5];
    const float* qg = (const float*)d_in[6];
    const float* kg = (const float*)d_in[7];
    const float* cs = (const float*)d_in[8];
    const float* sn = (const float*)d_in[9];

    char* ws = (char*)d_ws;
    int8_t* q8 = (int8_t*)(ws);                  // 24 MiB: wq,wk,wv,wo + hidden
    float* sAll = (float*)(ws + 25165824);       // 12288 fp32 scales
    u16* qb = (u16*)(ws + 25214976);             // Q bf16 (B,T,C)
    u16* kb = (u16*)(ws + 41992192);             // K bf16
    u16* vt = (u16*)(ws + 75546624);             // V^T bf16 (B,H,HD,T)
    float* Obuf = (float*)(ws + 92323840);       // O fp32 (B,T,C)
    int8_t* hid8 = q8 + 16777216;                // hidden int8 (reused for O)
    float* sx = sAll + 8192;                     // hidden scales (reused for O)

    quant_all<<<12288, 256, 0, stream>>>(wq, wk, wv, wo, hidden, q8, sAll);

    // z=0 -> Q bf16 (qb), z=1 -> K bf16 (kb), z=2 -> V written TRANSPOSED to vt
    gemm_i8<<<dim3(512, 3), 256, 0, stream>>>(hid8, q8, sx, sAll, (void*)qb,
                                              4194304LL, 2048LL, 8388608LL, 0,
                                              vt);

    norm_rope2<<<8192, 256, 0, stream>>>(qb, kb, qg, kg, cs, sn);

    flash<<<dim3(1024), 256, 0, stream>>>(qb, kb, vt, mask, Obuf);

    quant_rows<<<4096, 256, 0, stream>>>(Obuf, hid8, sx);
    gemm_i8<<<dim3(512, 1), 256, 0, stream>>>(hid8, q8 + 12582912, sx,
                                              sAll + 6144, d_out, 0LL, 0LL,
                                              0LL, 1, nullptr);
}

// Round 10
// 334.382 us; speedup vs baseline: 1.2723x; 1.0113x over previous
//
#include <hip/hip_runtime.h>
#include <stdint.h>

typedef unsigned short u16;
typedef unsigned int u32;
typedef int v4i __attribute__((ext_vector_type(4)));
typedef float v4f __attribute__((ext_vector_type(4)));
typedef short v8s __attribute__((ext_vector_type(8)));

#define Bn 2
#define Tn 2048
#define Cn 2048
#define Hn 16
#define HDn 128

__device__ __forceinline__ float b2f(u16 u) {
    u32 x = ((u32)u) << 16;
    float f;
    __builtin_memcpy(&f, &x, 4);
    return f;
}
__device__ __forceinline__ u16 f2b(float f) {
    u32 x;
    __builtin_memcpy(&x, &f, 4);
    u32 r = (x + 0x7fffu + ((x >> 16) & 1u)) >> 16;
    return (u16)r;
}
// v_cvt_pk_bf16_f32: packed RNE f32->bf16 (1 VALU op); asm form validated R6.
__device__ __forceinline__ u32 cvtpk(float a, float b) {
    u32 r;
    asm("v_cvt_pk_bf16_f32 %0, %1, %2" : "=v"(r) : "v"(a), "v"(b));
    return r;
}
// single-value RNE f32->bf16 in ONE op (vs 5-op bit-trick f2b)
__device__ __forceinline__ u16 f2b_fast(float f) {
    u32 r;
    asm("v_cvt_pk_bf16_f32 %0, %1, %2" : "=v"(r) : "v"(f), "v"(f));
    return (u16)r;
}

__device__ __forceinline__ void async16(const void* g, void* l) {
    __builtin_amdgcn_global_load_lds(
        (const __attribute__((address_space(1))) u32*)g,
        (__attribute__((address_space(3))) u32*)l, 16, 0, 0);
}

// ---------- fused row quantization: 4 weight matrices + hidden ----------
__global__ __launch_bounds__(256) void quant_all(
    const float* __restrict__ w0, const float* __restrict__ w1,
    const float* __restrict__ w2, const float* __restrict__ w3,
    const float* __restrict__ hid, int8_t* __restrict__ Q,
    float* __restrict__ S) {
    int r = blockIdx.x;
    const float* src;
    int ro;
    if (r < 2048) { src = w0; ro = r; }
    else if (r < 4096) { src = w1; ro = r - 2048; }
    else if (r < 6144) { src = w2; ro = r - 4096; }
    else if (r < 8192) { src = w3; ro = r - 6144; }
    else { src = hid; ro = r - 8192; }
    const float* x = src + (size_t)ro * Cn;
    int tid = threadIdx.x;
    float4 v0 = ((const float4*)x)[tid * 2];
    float4 v1 = ((const float4*)x)[tid * 2 + 1];
    float a[8] = {v0.x, v0.y, v0.z, v0.w, v1.x, v1.y, v1.z, v1.w};
    float m = 0.f;
#pragma unroll
    for (int i = 0; i < 8; i++) m = fmaxf(m, fabsf(a[i]));
#pragma unroll
    for (int o = 32; o; o >>= 1) m = fmaxf(m, __shfl_xor(m, o));
    __shared__ float sm[4];
    if ((tid & 63) == 0) sm[tid >> 6] = m;
    __syncthreads();
    m = fmaxf(fmaxf(sm[0], sm[1]), fmaxf(sm[2], sm[3]));
    float s = m * (1.0f / 127.0f) + 1e-8f;
    if (tid == 0) S[r] = s;
    u32 lo = 0, hi = 0;
#pragma unroll
    for (int i = 0; i < 8; i++) {
        float q = rintf(fminf(127.f, fmaxf(-127.f, a[i] / s)));
        int qi = (int)q;
        u32 byte = (u32)(qi & 0xff);
        if (i < 4) lo |= byte << (8 * i);
        else hi |= byte << (8 * (i - 4));
    }
    u32* qp = (u32*)(Q + (size_t)r * Cn);
    qp[tid * 2] = lo;
    qp[tid * 2 + 1] = hi;
}

// ---------- row quantization (fp32, attention output O) ----------
__global__ __launch_bounds__(256) void quant_rows(const float* __restrict__ X,
                                                  int8_t* __restrict__ Q,
                                                  float* __restrict__ S) {
    int r = blockIdx.x;
    const float* x = X + (size_t)r * Cn;
    int tid = threadIdx.x;
    float4 v0 = ((const float4*)x)[tid * 2];
    float4 v1 = ((const float4*)x)[tid * 2 + 1];
    float a[8] = {v0.x, v0.y, v0.z, v0.w, v1.x, v1.y, v1.z, v1.w};
    float m = 0.f;
#pragma unroll
    for (int i = 0; i < 8; i++) m = fmaxf(m, fabsf(a[i]));
#pragma unroll
    for (int o = 32; o; o >>= 1) m = fmaxf(m, __shfl_xor(m, o));
    __shared__ float sm[4];
    if ((tid & 63) == 0) sm[tid >> 6] = m;
    __syncthreads();
    m = fmaxf(fmaxf(sm[0], sm[1]), fmaxf(sm[2], sm[3]));
    float s = m * (1.0f / 127.0f) + 1e-8f;
    if (tid == 0) S[r] = s;
    u32 lo = 0, hi = 0;
#pragma unroll
    for (int i = 0; i < 8; i++) {
        float q = rintf(fminf(127.f, fmaxf(-127.f, a[i] / s)));
        int qi = (int)q;
        u32 byte = (u32)(qi & 0xff);
        if (i < 4) lo |= byte << (8 * i);
        else hi |= byte << (8 * (i - 4));
    }
    u32* qp = (u32*)(Q + (size_t)r * Cn);
    qp[tid * 2] = lo;
    qp[tid * 2 + 1] = hi;
}

// ---------- int8 GEMM (R9: XCD-chunked mapping + fused V-transpose).
// R10: epilogue bf16 conversions via 1-op cvtpk instead of 5-op f2b. ----------
__global__ __launch_bounds__(256) void gemm_i8(
    const int8_t* __restrict__ A, const int8_t* __restrict__ Bw,
    const float* __restrict__ sA, const float* __restrict__ sB,
    void* __restrict__ Co, long long bStride, long long sbStride,
    long long cStride, int fp32out, u16* __restrict__ vtOut) {
    int wg = blockIdx.x, z = blockIdx.y;
    Bw += (size_t)z * bStride;
    sB += (size_t)z * sbStride;
    const int K = 2048, N = 2048;
    __shared__ int8_t As[128 * 64];
    __shared__ int8_t Bs[128 * 64];
    int xcd = wg & 7, c = wg >> 3;
    int m0 = ((xcd >> 1) * 8 + (c >> 3)) * 128;
    int n0 = ((xcd & 1) * 8 + (c & 7)) * 128;
    int tid = threadIdx.x, w = tid >> 6, lane = tid & 63;
    int quad = lane >> 4, l15 = lane & 15;
    int wy = w >> 1, wx = w & 1;
    const v4i zi = {0, 0, 0, 0};
    v4i acc[4][4];
#pragma unroll
    for (int i = 0; i < 4; i++)
#pragma unroll
        for (int j = 0; j < 4; j++) acc[i][j] = zi;
    int lrow = lane >> 2;
    int slot = lane & 3;
    int srow = w * 32 + lrow;
    int klog = ((slot ^ (lrow & 3)) * 16);
    const int8_t* ga = A + (size_t)(m0 + srow) * K + klog;
    const int8_t* gb = Bw + (size_t)(n0 + srow) * K + klog;
    int8_t* la = &As[srow * 64 + slot * 16];
    int8_t* lb = &Bs[srow * 64 + slot * 16];
    for (int k0 = 0; k0 < K; k0 += 64) {
        async16(ga + k0, la);
        async16(ga + k0 + (size_t)16 * K, la + 16 * 64);
        async16(gb + k0, lb);
        async16(gb + k0 + (size_t)16 * K, lb + 16 * 64);
        __syncthreads();
        int swz = (quad ^ (l15 & 3)) * 16;
        v4i af[4], bf4[4];
#pragma unroll
        for (int i = 0; i < 4; i++)
            af[i] = *(const v4i*)&As[(wy * 64 + i * 16 + l15) * 64 + swz];
#pragma unroll
        for (int j = 0; j < 4; j++)
            bf4[j] = *(const v4i*)&Bs[(wx * 64 + j * 16 + l15) * 64 + swz];
#pragma unroll
        for (int i = 0; i < 4; i++)
#pragma unroll
            for (int j = 0; j < 4; j++)
                acc[i][j] = __builtin_amdgcn_mfma_i32_16x16x64_i8(
                    af[i], bf4[j], acc[i][j], 0, 0, 0);
        __syncthreads();
    }
    bool vmode = (z == 2) && (vtOut != nullptr);
#pragma unroll
    for (int i = 0; i < 4; i++) {
        int mb = m0 + wy * 64 + i * 16 + quad * 4;
        float s0 = sA[mb], s1 = sA[mb + 1], s2 = sA[mb + 2], s3 = sA[mb + 3];
#pragma unroll
        for (int j = 0; j < 4; j++) {
            int n = n0 + wx * 64 + j * 16 + l15;
            float sb = sB[n];
            if (fp32out) {
                float* cp = (float*)Co + (size_t)cStride * z + (size_t)mb * N + n;
                cp[0] = (float)acc[i][j][0] * s0 * sb;
                cp[N] = (float)acc[i][j][1] * s1 * sb;
                cp[2 * N] = (float)acc[i][j][2] * s2 * sb;
                cp[3 * N] = (float)acc[i][j][3] * s3 * sb;
            } else if (vmode) {
                // V element (b,t,h,d): row mb = b*2048+t, col n = h*128+d.
                // Vt[bh][d][t]; 4 acc rows = t..t+3 (t%4==0) -> one 8B store.
                int bidx = mb >> 11, t = mb & 2047;
                int hh = n >> 7, d = n & 127;
                u16* vp =
                    vtOut + (((size_t)(bidx * 16 + hh) * 128 + d) * 2048 + t);
                u32 lo2 = cvtpk((float)acc[i][j][0] * s0 * sb,
                                (float)acc[i][j][1] * s1 * sb);
                u32 hi2 = cvtpk((float)acc[i][j][2] * s2 * sb,
                                (float)acc[i][j][3] * s3 * sb);
                *(uint2*)vp = make_uint2(lo2, hi2);
            } else {
                u16* cp = (u16*)Co + (size_t)cStride * z + (size_t)mb * N + n;
                cp[0] = f2b_fast((float)acc[i][j][0] * s0 * sb);
                cp[N] = f2b_fast((float)acc[i][j][1] * s1 * sb);
                cp[2 * N] = f2b_fast((float)acc[i][j][2] * s2 * sb);
                cp[3 * N] = f2b_fast((float)acc[i][j][3] * s3 * sb);
            }
        }
    }
}

// ---------- fused RMSNorm + RoPE (Q gets 1/sqrt(HD) folded) ----------
__global__ __launch_bounds__(256) void norm_rope2(u16* __restrict__ Qb,
                                                  u16* __restrict__ Kb,
                                                  const float* __restrict__ qg,
                                                  const float* __restrict__ kg,
                                                  const float* __restrict__ cs,
                                                  const float* __restrict__ sn) {
    int row = blockIdx.x;
    int isq = row < 4096;
    row &= 4095;
    u16* x = (isq ? Qb : Kb) + (size_t)row * Cn;
    const float* g = isq ? qg : kg;
    float ps = isq ? 0.08838834764831845f : 1.0f;
    int t = row & (Tn - 1);
    int tid = threadIdx.x;
    uint4 raw = ((const uint4*)x)[tid];
    u16 us[8];
    us[0] = raw.x & 0xffff; us[1] = raw.x >> 16;
    us[2] = raw.y & 0xffff; us[3] = raw.y >> 16;
    us[4] = raw.z & 0xffff; us[5] = raw.z >> 16;
    us[6] = raw.w & 0xffff; us[7] = raw.w >> 16;
    float v[8];
#pragma unroll
    for (int i = 0; i < 8; i++) v[i] = b2f(us[i]);
    float ss = 0.f;
#pragma unroll
    for (int i = 0; i < 8; i++) ss += v[i] * v[i];
#pragma unroll
    for (int o = 32; o; o >>= 1) ss += __shfl_xor(ss, o);
    __shared__ float sm[4];
    if ((tid & 63) == 0) sm[tid >> 6] = ss;
    __syncthreads();
    ss = sm[0] + sm[1] + sm[2] + sm[3];
    float r = rsqrtf(ss * (1.f / 2048.f) + 1e-6f) * ps;
    float4 g0 = ((const float4*)g)[tid * 2];
    float4 g1 = ((const float4*)g)[tid * 2 + 1];
    float n[8];
    n[0] = v[0] * r * g0.x; n[1] = v[1] * r * g0.y;
    n[2] = v[2] * r * g0.z; n[3] = v[3] * r * g0.w;
    n[4] = v[4] * r * g1.x; n[5] = v[5] * r * g1.y;
    n[6] = v[6] * r * g1.z; n[7] = v[7] * r * g1.w;
    int pi = (tid & 15) * 4;
    float4 c4 = *(const float4*)(cs + t * 64 + pi);
    float4 s4 = *(const float4*)(sn + t * 64 + pi);
    float o[8];
    o[0] = n[0] * c4.x - n[1] * s4.x; o[1] = n[0] * s4.x + n[1] * c4.x;
    o[2] = n[2] * c4.y - n[3] * s4.y; o[3] = n[2] * s4.y + n[3] * c4.y;
    o[4] = n[4] * c4.z - n[5] * s4.z; o[5] = n[4] * s4.z + n[5] * c4.z;
    o[6] = n[6] * c4.w - n[7] * s4.w; o[7] = n[6] * s4.w + n[7] * c4.w;
    uint4 out;
    out.x = cvtpk(o[0], o[1]);
    out.y = cvtpk(o[2], o[3]);
    out.z = cvtpk(o[4], o[5]);
    out.w = cvtpk(o[6], o[7]);
    ((uint4*)x)[tid] = out;
}

// ---------- flash v7 (R5/R8 proven structure) + 1-op bf16 convert ----------
__global__ __launch_bounds__(256, 3) void flash(const u16* __restrict__ Qb,
                                                const u16* __restrict__ Kb,
                                                const u16* __restrict__ Vt,
                                                const int* __restrict__ mask,
                                                float* __restrict__ O) {
    int id = blockIdx.x;
    int bh = (id & 7) + 8 * (id >> 8);  // XCD-aware (proven: FETCH 93->21MB)
    int qt = (id >> 3) & 31;
    int b = bh >> 4, h = bh & 15;
    int L = mask[b];
    int nkfull = L >> 6;
    int nk = (L + 63) >> 6;
    __shared__ u16 Ks[2][64 * 128];
    __shared__ u16 Ps[2][64 * 72];
    __shared__ float sred[256];
    __shared__ float sinv[64];
    int tid = threadIdx.x, w = tid >> 6, lane = tid & 63;
    int quad = lane >> 4, l15 = lane & 15;

    v8s aq[4][4];
#pragma unroll
    for (int i = 0; i < 4; i++)
#pragma unroll
        for (int kk = 0; kk < 4; kk++)
            aq[i][kk] = *(const v8s*)(Qb +
                                      ((size_t)b * Tn + qt * 64 + i * 16 + l15) * Cn +
                                      h * HDn + kk * 32 + quad * 8);

    const u16* ksp[4];
    int kdo[4];
#pragma unroll
    for (int cc = 0; cc < 4; cc++) {
        int c = w * 4 + cc;
        int rk = c * 4 + (lane >> 4);
        int sk = lane & 15;
        int lgk = sk ^ (rk & 7);
        ksp[cc] = Kb + ((size_t)b * Tn + rk) * Cn + h * HDn + lgk * 8;
        kdo[cc] = rk * 128 + sk * 8;
    }

    const u16* vp0 = Vt + ((size_t)bh * HDn + 2 * w * 16 + l15) * Tn + quad * 8;
    const u16* vp1 = vp0 + 16 * Tn;

    float sum16[16];
#pragma unroll
    for (int j = 0; j < 16; j++) sum16[j] = 0.f;
    const v4f zf = {0.f, 0.f, 0.f, 0.f};
    v4f oacc[4][2];
#pragma unroll
    for (int m = 0; m < 4; m++) {
        oacc[m][0] = zf;
        oacc[m][1] = zf;
    }

#pragma unroll
    for (int cc = 0; cc < 4; cc++) {
        async16(ksp[cc], &Ks[0][kdo[cc]]);
        ksp[cc] += (size_t)64 * Cn;
    }
    __syncthreads();

    int cur = 0;
    for (int kt = 0; kt < nk; kt++) {
        if (kt + 1 < nk) {
#pragma unroll
            for (int cc = 0; cc < 4; cc++) {
                async16(ksp[cc], &Ks[cur ^ 1][kdo[cc]]);
                ksp[cc] += (size_t)64 * Cn;
            }
        }
        v8s bv00 = *(const v8s*)(vp0);
        v8s bv10 = *(const v8s*)(vp0 + 32);
        v8s bv01 = *(const v8s*)(vp1);
        v8s bv11 = *(const v8s*)(vp1 + 32);
        vp0 += 64;
        vp1 += 64;
        v4f sacc[4] = {zf, zf, zf, zf};
        const u16* krow = &Ks[cur][(w * 16 + l15) * 128];
#pragma unroll
        for (int kk = 0; kk < 4; kk++) {
            v8s bk = *(const v8s*)(krow + ((((kk * 4 + quad) ^ (l15 & 7))) << 3));
#pragma unroll
            for (int i = 0; i < 4; i++)
                sacc[i] = __builtin_amdgcn_mfma_f32_16x16x32_bf16(aq[i][kk], bk,
                                                                  sacc[i], 0, 0, 0);
        }
        bool valid = (kt < nkfull) || ((kt * 64 + w * 16 + l15) < L);
#pragma unroll
        for (int i = 0; i < 4; i++)
#pragma unroll
            for (int r2 = 0; r2 < 4; r2++) {
                float p = valid ? __expf(sacc[i][r2]) : 0.f;
                sum16[i * 4 + r2] += p;
                Ps[cur][(i * 16 + quad * 4 + r2) * 72 + w * 16 + l15] =
                    f2b_fast(p);
            }
        __syncthreads();  // Ps[cur] visible; K(kt+1) staged; bv drained
#pragma unroll
        for (int kk2 = 0; kk2 < 2; kk2++) {
            v8s ap[4];
#pragma unroll
            for (int m = 0; m < 4; m++)
                ap[m] = *(const v8s*)(&Ps[cur][(m * 16 + l15) * 72 + kk2 * 32 +
                                               quad * 8]);
            v8s bva = kk2 ? bv10 : bv00;
            v8s bvb = kk2 ? bv11 : bv01;
#pragma unroll
            for (int m = 0; m < 4; m++) {
                oacc[m][0] = __builtin_amdgcn_mfma_f32_16x16x32_bf16(
                    ap[m], bva, oacc[m][0], 0, 0, 0);
                oacc[m][1] = __builtin_amdgcn_mfma_f32_16x16x32_bf16(
                    ap[m], bvb, oacc[m][1], 0, 0, 0);
            }
        }
        cur ^= 1;
    }
#pragma unroll
    for (int j = 0; j < 16; j++) {
        float s = sum16[j];
        s += __shfl_xor(s, 1);
        s += __shfl_xor(s, 2);
        s += __shfl_xor(s, 4);
        s += __shfl_xor(s, 8);
        sum16[j] = s;
    }
    if (l15 == 0) {
#pragma unroll
        for (int i = 0; i < 4; i++)
#pragma unroll
            for (int r2 = 0; r2 < 4; r2++)
                sred[w * 64 + i * 16 + quad * 4 + r2] = sum16[i * 4 + r2];
    }
    __syncthreads();
    if (tid < 64)
        sinv[tid] =
            1.f / (sred[tid] + sred[64 + tid] + sred[128 + tid] + sred[192 + tid]);
    __syncthreads();
#pragma unroll
    for (int m = 0; m < 4; m++)
#pragma unroll
        for (int r2 = 0; r2 < 4; r2++) {
            float inv = sinv[m * 16 + quad * 4 + r2];
            int row = qt * 64 + m * 16 + quad * 4 + r2;
#pragma unroll
            for (int nbi = 0; nbi < 2; nbi++) {
                int d = h * HDn + (2 * w + nbi) * 16 + l15;
                O[((size_t)b * Tn + row) * Cn + d] = oacc[m][nbi][r2] * inv;
            }
        }
}

extern "C" void kernel_launch(void* const* d_in, const int* in_sizes, int n_in,
                              void* d_out, int out_size, void* d_ws,
                              size_t ws_size, hipStream_t stream) {
    const float* hidden = (const float*)d_in[0];
    const int* mask = (const int*)d_in[1];
    const float* wq = (const float*)d_in[2];
    const float* wk = (const float*)d_in[3];
    const float* wv = (const float*)d_in[4];
    const float* wo = (const float*)d_in[5];
    const float* qg = (const float*)d_in[6];
    const float* kg = (const float*)d_in[7];
    const float* cs = (const float*)d_in[8];
    const float* sn = (const float*)d_in[9];

    char* ws = (char*)d_ws;
    int8_t* q8 = (int8_t*)(ws);                  // 24 MiB: wq,wk,wv,wo + hidden
    float* sAll = (float*)(ws + 25165824);       // 12288 fp32 scales
    u16* qb = (u16*)(ws + 25214976);             // Q bf16 (B,T,C)
    u16* kb = (u16*)(ws + 41992192);             // K bf16
    u16* vt = (u16*)(ws + 75546624);             // V^T bf16 (B,H,HD,T)
    float* Obuf = (float*)(ws + 92323840);       // O fp32 (B,T,C)
    int8_t* hid8 = q8 + 16777216;                // hidden int8 (reused for O)
    float* sx = sAll + 8192;                     // hidden scales (reused for O)

    quant_all<<<12288, 256, 0, stream>>>(wq, wk, wv, wo, hidden, q8, sAll);

    // z=0 -> Q bf16 (qb), z=1 -> K bf16 (kb), z=2 -> V written TRANSPOSED to vt
    gemm_i8<<<dim3(512, 3), 256, 0, stream>>>(hid8, q8, sx, sAll, (void*)qb,
                                              4194304LL, 2048LL, 8388608LL, 0,
                                              vt);

    norm_rope2<<<8192, 256, 0, stream>>>(qb, kb, qg, kg, cs, sn);

    flash<<<dim3(1024), 256, 0, stream>>>(qb, kb, vt, mask, Obuf);

    quant_rows<<<4096, 256, 0, stream>>>(Obuf, hid8, sx);
    gemm_i8<<<dim3(512, 1), 256, 0, stream>>>(hid8, q8 + 12582912, sx,
                                              sAll + 6144, d_out, 0LL, 0LL,
                                              0LL, 1, nullptr);
}

// Round 11
// 329.066 us; speedup vs baseline: 1.2929x; 1.0162x over previous
//
#include <hip/hip_runtime.h>
#include <stdint.h>

typedef unsigned short u16;
typedef unsigned int u32;
typedef int v4i __attribute__((ext_vector_type(4)));
typedef float v4f __attribute__((ext_vector_type(4)));
typedef short v8s __attribute__((ext_vector_type(8)));

#define Bn 2
#define Tn 2048
#define Cn 2048
#define Hn 16
#define HDn 128

__device__ __forceinline__ float b2f(u16 u) {
    u32 x = ((u32)u) << 16;
    float f;
    __builtin_memcpy(&f, &x, 4);
    return f;
}
__device__ __forceinline__ u16 f2b(float f) {
    u32 x;
    __builtin_memcpy(&x, &f, 4);
    u32 r = (x + 0x7fffu + ((x >> 16) & 1u)) >> 16;
    return (u16)r;
}
// v_cvt_pk_bf16_f32: packed RNE f32->bf16 (1 VALU op); validated R6/R10.
__device__ __forceinline__ u32 cvtpk(float a, float b) {
    u32 r;
    asm("v_cvt_pk_bf16_f32 %0, %1, %2" : "=v"(r) : "v"(a), "v"(b));
    return r;
}
__device__ __forceinline__ u16 f2b_fast(float f) {
    u32 r;
    asm("v_cvt_pk_bf16_f32 %0, %1, %2" : "=v"(r) : "v"(f), "v"(f));
    return (u16)r;
}

__device__ __forceinline__ void async16(const void* g, void* l) {
    __builtin_amdgcn_global_load_lds(
        (const __attribute__((address_space(1))) u32*)g,
        (__attribute__((address_space(3))) u32*)l, 16, 0, 0);
}

// ---------- fused row quantization: 4 weight matrices + hidden ----------
__global__ __launch_bounds__(256) void quant_all(
    const float* __restrict__ w0, const float* __restrict__ w1,
    const float* __restrict__ w2, const float* __restrict__ w3,
    const float* __restrict__ hid, int8_t* __restrict__ Q,
    float* __restrict__ S) {
    int r = blockIdx.x;
    const float* src;
    int ro;
    if (r < 2048) { src = w0; ro = r; }
    else if (r < 4096) { src = w1; ro = r - 2048; }
    else if (r < 6144) { src = w2; ro = r - 4096; }
    else if (r < 8192) { src = w3; ro = r - 6144; }
    else { src = hid; ro = r - 8192; }
    const float* x = src + (size_t)ro * Cn;
    int tid = threadIdx.x;
    float4 v0 = ((const float4*)x)[tid * 2];
    float4 v1 = ((const float4*)x)[tid * 2 + 1];
    float a[8] = {v0.x, v0.y, v0.z, v0.w, v1.x, v1.y, v1.z, v1.w};
    float m = 0.f;
#pragma unroll
    for (int i = 0; i < 8; i++) m = fmaxf(m, fabsf(a[i]));
#pragma unroll
    for (int o = 32; o; o >>= 1) m = fmaxf(m, __shfl_xor(m, o));
    __shared__ float sm[4];
    if ((tid & 63) == 0) sm[tid >> 6] = m;
    __syncthreads();
    m = fmaxf(fmaxf(sm[0], sm[1]), fmaxf(sm[2], sm[3]));
    float s = m * (1.0f / 127.0f) + 1e-8f;
    if (tid == 0) S[r] = s;
    u32 lo = 0, hi = 0;
#pragma unroll
    for (int i = 0; i < 8; i++) {
        float q = rintf(fminf(127.f, fmaxf(-127.f, a[i] / s)));
        int qi = (int)q;
        u32 byte = (u32)(qi & 0xff);
        if (i < 4) lo |= byte << (8 * i);
        else hi |= byte << (8 * (i - 4));
    }
    u32* qp = (u32*)(Q + (size_t)r * Cn);
    qp[tid * 2] = lo;
    qp[tid * 2 + 1] = hi;
}

// ---------- row quantization (fp32, attention output O) ----------
__global__ __launch_bounds__(256) void quant_rows(const float* __restrict__ X,
                                                  int8_t* __restrict__ Q,
                                                  float* __restrict__ S) {
    int r = blockIdx.x;
    const float* x = X + (size_t)r * Cn;
    int tid = threadIdx.x;
    float4 v0 = ((const float4*)x)[tid * 2];
    float4 v1 = ((const float4*)x)[tid * 2 + 1];
    float a[8] = {v0.x, v0.y, v0.z, v0.w, v1.x, v1.y, v1.z, v1.w};
    float m = 0.f;
#pragma unroll
    for (int i = 0; i < 8; i++) m = fmaxf(m, fabsf(a[i]));
#pragma unroll
    for (int o = 32; o; o >>= 1) m = fmaxf(m, __shfl_xor(m, o));
    __shared__ float sm[4];
    if ((tid & 63) == 0) sm[tid >> 6] = m;
    __syncthreads();
    m = fmaxf(fmaxf(sm[0], sm[1]), fmaxf(sm[2], sm[3]));
    float s = m * (1.0f / 127.0f) + 1e-8f;
    if (tid == 0) S[r] = s;
    u32 lo = 0, hi = 0;
#pragma unroll
    for (int i = 0; i < 8; i++) {
        float q = rintf(fminf(127.f, fmaxf(-127.f, a[i] / s)));
        int qi = (int)q;
        u32 byte = (u32)(qi & 0xff);
        if (i < 4) lo |= byte << (8 * i);
        else hi |= byte << (8 * (i - 4));
    }
    u32* qp = (u32*)(Q + (size_t)r * Cn);
    qp[tid * 2] = lo;
    qp[tid * 2 + 1] = hi;
}

// ---------- int8 GEMM (R9 XCD-chunked + R8 fused V-transpose + R10 cvtpk) ----
__global__ __launch_bounds__(256) void gemm_i8(
    const int8_t* __restrict__ A, const int8_t* __restrict__ Bw,
    const float* __restrict__ sA, const float* __restrict__ sB,
    void* __restrict__ Co, long long bStride, long long sbStride,
    long long cStride, int fp32out, u16* __restrict__ vtOut) {
    int wg = blockIdx.x, z = blockIdx.y;
    Bw += (size_t)z * bStride;
    sB += (size_t)z * sbStride;
    const int K = 2048, N = 2048;
    __shared__ int8_t As[128 * 64];
    __shared__ int8_t Bs[128 * 64];
    int xcd = wg & 7, c = wg >> 3;
    int m0 = ((xcd >> 1) * 8 + (c >> 3)) * 128;
    int n0 = ((xcd & 1) * 8 + (c & 7)) * 128;
    int tid = threadIdx.x, w = tid >> 6, lane = tid & 63;
    int quad = lane >> 4, l15 = lane & 15;
    int wy = w >> 1, wx = w & 1;
    const v4i zi = {0, 0, 0, 0};
    v4i acc[4][4];
#pragma unroll
    for (int i = 0; i < 4; i++)
#pragma unroll
        for (int j = 0; j < 4; j++) acc[i][j] = zi;
    int lrow = lane >> 2;
    int slot = lane & 3;
    int srow = w * 32 + lrow;
    int klog = ((slot ^ (lrow & 3)) * 16);
    const int8_t* ga = A + (size_t)(m0 + srow) * K + klog;
    const int8_t* gb = Bw + (size_t)(n0 + srow) * K + klog;
    int8_t* la = &As[srow * 64 + slot * 16];
    int8_t* lb = &Bs[srow * 64 + slot * 16];
    for (int k0 = 0; k0 < K; k0 += 64) {
        async16(ga + k0, la);
        async16(ga + k0 + (size_t)16 * K, la + 16 * 64);
        async16(gb + k0, lb);
        async16(gb + k0 + (size_t)16 * K, lb + 16 * 64);
        __syncthreads();
        int swz = (quad ^ (l15 & 3)) * 16;
        v4i af[4], bf4[4];
#pragma unroll
        for (int i = 0; i < 4; i++)
            af[i] = *(const v4i*)&As[(wy * 64 + i * 16 + l15) * 64 + swz];
#pragma unroll
        for (int j = 0; j < 4; j++)
            bf4[j] = *(const v4i*)&Bs[(wx * 64 + j * 16 + l15) * 64 + swz];
#pragma unroll
        for (int i = 0; i < 4; i++)
#pragma unroll
            for (int j = 0; j < 4; j++)
                acc[i][j] = __builtin_amdgcn_mfma_i32_16x16x64_i8(
                    af[i], bf4[j], acc[i][j], 0, 0, 0);
        __syncthreads();
    }
    bool vmode = (z == 2) && (vtOut != nullptr);
#pragma unroll
    for (int i = 0; i < 4; i++) {
        int mb = m0 + wy * 64 + i * 16 + quad * 4;
        float s0 = sA[mb], s1 = sA[mb + 1], s2 = sA[mb + 2], s3 = sA[mb + 3];
#pragma unroll
        for (int j = 0; j < 4; j++) {
            int n = n0 + wx * 64 + j * 16 + l15;
            float sb = sB[n];
            if (fp32out) {
                float* cp = (float*)Co + (size_t)cStride * z + (size_t)mb * N + n;
                cp[0] = (float)acc[i][j][0] * s0 * sb;
                cp[N] = (float)acc[i][j][1] * s1 * sb;
                cp[2 * N] = (float)acc[i][j][2] * s2 * sb;
                cp[3 * N] = (float)acc[i][j][3] * s3 * sb;
            } else if (vmode) {
                int bidx = mb >> 11, t = mb & 2047;
                int hh = n >> 7, d = n & 127;
                u16* vp =
                    vtOut + (((size_t)(bidx * 16 + hh) * 128 + d) * 2048 + t);
                u32 lo2 = cvtpk((float)acc[i][j][0] * s0 * sb,
                                (float)acc[i][j][1] * s1 * sb);
                u32 hi2 = cvtpk((float)acc[i][j][2] * s2 * sb,
                                (float)acc[i][j][3] * s3 * sb);
                *(uint2*)vp = make_uint2(lo2, hi2);
            } else {
                u16* cp = (u16*)Co + (size_t)cStride * z + (size_t)mb * N + n;
                cp[0] = f2b_fast((float)acc[i][j][0] * s0 * sb);
                cp[N] = f2b_fast((float)acc[i][j][1] * s1 * sb);
                cp[2 * N] = f2b_fast((float)acc[i][j][2] * s2 * sb);
                cp[3 * N] = f2b_fast((float)acc[i][j][3] * s3 * sb);
            }
        }
    }
}

// ---------- fused RMSNorm + RoPE (Q gets 1/sqrt(HD) folded) ----------
__global__ __launch_bounds__(256) void norm_rope2(u16* __restrict__ Qb,
                                                  u16* __restrict__ Kb,
                                                  const float* __restrict__ qg,
                                                  const float* __restrict__ kg,
                                                  const float* __restrict__ cs,
                                                  const float* __restrict__ sn) {
    int row = blockIdx.x;
    int isq = row < 4096;
    row &= 4095;
    u16* x = (isq ? Qb : Kb) + (size_t)row * Cn;
    const float* g = isq ? qg : kg;
    float ps = isq ? 0.08838834764831845f : 1.0f;
    int t = row & (Tn - 1);
    int tid = threadIdx.x;
    uint4 raw = ((const uint4*)x)[tid];
    u16 us[8];
    us[0] = raw.x & 0xffff; us[1] = raw.x >> 16;
    us[2] = raw.y & 0xffff; us[3] = raw.y >> 16;
    us[4] = raw.z & 0xffff; us[5] = raw.z >> 16;
    us[6] = raw.w & 0xffff; us[7] = raw.w >> 16;
    float v[8];
#pragma unroll
    for (int i = 0; i < 8; i++) v[i] = b2f(us[i]);
    float ss = 0.f;
#pragma unroll
    for (int i = 0; i < 8; i++) ss += v[i] * v[i];
#pragma unroll
    for (int o = 32; o; o >>= 1) ss += __shfl_xor(ss, o);
    __shared__ float sm[4];
    if ((tid & 63) == 0) sm[tid >> 6] = ss;
    __syncthreads();
    ss = sm[0] + sm[1] + sm[2] + sm[3];
    float r = rsqrtf(ss * (1.f / 2048.f) + 1e-6f) * ps;
    float4 g0 = ((const float4*)g)[tid * 2];
    float4 g1 = ((const float4*)g)[tid * 2 + 1];
    float n[8];
    n[0] = v[0] * r * g0.x; n[1] = v[1] * r * g0.y;
    n[2] = v[2] * r * g0.z; n[3] = v[3] * r * g0.w;
    n[4] = v[4] * r * g1.x; n[5] = v[5] * r * g1.y;
    n[6] = v[6] * r * g1.z; n[7] = v[7] * r * g1.w;
    int pi = (tid & 15) * 4;
    float4 c4 = *(const float4*)(cs + t * 64 + pi);
    float4 s4 = *(const float4*)(sn + t * 64 + pi);
    float o[8];
    o[0] = n[0] * c4.x - n[1] * s4.x; o[1] = n[0] * s4.x + n[1] * c4.x;
    o[2] = n[2] * c4.y - n[3] * s4.y; o[3] = n[2] * s4.y + n[3] * c4.y;
    o[4] = n[4] * c4.z - n[5] * s4.z; o[5] = n[4] * s4.z + n[5] * c4.z;
    o[6] = n[6] * c4.w - n[7] * s4.w; o[7] = n[6] * s4.w + n[7] * c4.w;
    uint4 out;
    out.x = cvtpk(o[0], o[1]);
    out.y = cvtpk(o[2], o[3]);
    out.z = cvtpk(o[4], o[5]);
    out.w = cvtpk(o[6], o[7]);
    ((uint4*)x)[tid] = out;
}

// ---------- flash v9: 3-deep K pipeline + counted vmcnt barrier (T4) ----------
// The old __syncthreads() forced vmcnt(0): every tile drained its own
// K-prefetch issued only ~QK+exp earlier -> exposed K latency each tile.
// Now: prologue stages K(0),K(1); tile kt issues V(kt) then K-pref(kt+2);
// barrier = {s_waitcnt vmcnt(4) lgkmcnt(0); s_barrier; sched_barrier}.
// vmcnt(4) retires everything except the newest 4 ops (= K-pref(kt+2)):
//   K-pref(kt+1) [issued tile kt-1, needed by QK(kt+1)]  -> retired ✓
//   V(kt)        [needed by PV(kt) now; compiler also tracks] -> retired ✓
//   K-pref(kt+2) [deadline barrier(kt+1)] -> stays in flight ✓
// lgkmcnt(0) preserves Ps write->read visibility. Buffer reuse check:
// Ks[c2]'s previous readers (QK, 3 tiles ago) retired at that barrier.
// LDS 67.5KB -> 2 blocks/CU (traded for true 2-tile prefetch depth).
__global__ __launch_bounds__(256, 2) void flash(const u16* __restrict__ Qb,
                                                const u16* __restrict__ Kb,
                                                const u16* __restrict__ Vt,
                                                const int* __restrict__ mask,
                                                float* __restrict__ O) {
    int id = blockIdx.x;
    int bh = (id & 7) + 8 * (id >> 8);  // XCD-aware (proven: FETCH 93->21MB)
    int qt = (id >> 3) & 31;
    int b = bh >> 4, h = bh & 15;
    int L = mask[b];
    int nkfull = L >> 6;
    int nk = (L + 63) >> 6;
    __shared__ u16 Ks[3][64 * 128];
    __shared__ u16 Ps[2][64 * 72];
    __shared__ float sred[256];
    __shared__ float sinv[64];
    int tid = threadIdx.x, w = tid >> 6, lane = tid & 63;
    int quad = lane >> 4, l15 = lane & 15;

    v8s aq[4][4];
#pragma unroll
    for (int i = 0; i < 4; i++)
#pragma unroll
        for (int kk = 0; kk < 4; kk++)
            aq[i][kk] = *(const v8s*)(Qb +
                                      ((size_t)b * Tn + qt * 64 + i * 16 + l15) * Cn +
                                      h * HDn + kk * 32 + quad * 8);

    const u16* ksp[4];
    int kdo[4];
#pragma unroll
    for (int cc = 0; cc < 4; cc++) {
        int c = w * 4 + cc;
        int rk = c * 4 + (lane >> 4);
        int sk = lane & 15;
        int lgk = sk ^ (rk & 7);
        ksp[cc] = Kb + ((size_t)b * Tn + rk) * Cn + h * HDn + lgk * 8;
        kdo[cc] = rk * 128 + sk * 8;
    }

    const u16* vp0 = Vt + ((size_t)bh * HDn + 2 * w * 16 + l15) * Tn + quad * 8;
    const u16* vp1 = vp0 + 16 * Tn;

    float sum16[16];
#pragma unroll
    for (int j = 0; j < 16; j++) sum16[j] = 0.f;
    const v4f zf = {0.f, 0.f, 0.f, 0.f};
    v4f oacc[4][2];
#pragma unroll
    for (int m = 0; m < 4; m++) {
        oacc[m][0] = zf;
        oacc[m][1] = zf;
    }

    // prologue: stage K(0) and (if present) K(1)
#pragma unroll
    for (int cc = 0; cc < 4; cc++) {
        async16(ksp[cc], &Ks[0][kdo[cc]]);
        ksp[cc] += (size_t)64 * Cn;
    }
    if (nk > 1) {
#pragma unroll
        for (int cc = 0; cc < 4; cc++) {
            async16(ksp[cc], &Ks[1][kdo[cc]]);
            ksp[cc] += (size_t)64 * Cn;
        }
    }
    __syncthreads();

    int cur = 0;
    int c0 = 0, c1 = 1, c2 = 2;
    for (int kt = 0; kt < nk; kt++) {
        // V(kt) loads FIRST (older than the K-prefetch for vmcnt counting)
        v8s bv00 = *(const v8s*)(vp0);
        v8s bv10 = *(const v8s*)(vp0 + 32);
        v8s bv01 = *(const v8s*)(vp1);
        v8s bv11 = *(const v8s*)(vp1 + 32);
        vp0 += 64;
        vp1 += 64;
        __builtin_amdgcn_sched_barrier(0);  // pin V-issue before K-prefetch
        if (kt + 2 < nk) {
#pragma unroll
            for (int cc = 0; cc < 4; cc++) {
                async16(ksp[cc], &Ks[c2][kdo[cc]]);
                ksp[cc] += (size_t)64 * Cn;
            }
        }
        // QK^T from Ks[c0] (staged 2 tiles ago; retired at barrier(kt-1))
        v4f sacc[4] = {zf, zf, zf, zf};
        const u16* krow = &Ks[c0][(w * 16 + l15) * 128];
#pragma unroll
        for (int kk = 0; kk < 4; kk++) {
            v8s bk = *(const v8s*)(krow + ((((kk * 4 + quad) ^ (l15 & 7))) << 3));
#pragma unroll
            for (int i = 0; i < 4; i++)
                sacc[i] = __builtin_amdgcn_mfma_f32_16x16x32_bf16(aq[i][kk], bk,
                                                                  sacc[i], 0, 0, 0);
        }
        bool valid = (kt < nkfull) || ((kt * 64 + w * 16 + l15) < L);
#pragma unroll
        for (int i = 0; i < 4; i++)
#pragma unroll
            for (int r2 = 0; r2 < 4; r2++) {
                float p = valid ? __expf(sacc[i][r2]) : 0.f;
                sum16[i * 4 + r2] += p;
                Ps[cur][(i * 16 + quad * 4 + r2) * 72 + w * 16 + l15] =
                    f2b_fast(p);
            }
        // counted-vmcnt barrier: K-pref(kt+2) stays in flight
        asm volatile("s_waitcnt vmcnt(4) lgkmcnt(0)" ::: "memory");
        __builtin_amdgcn_s_barrier();
        __builtin_amdgcn_sched_barrier(0);
        // PV from Ps[cur] + V regs
#pragma unroll
        for (int kk2 = 0; kk2 < 2; kk2++) {
            v8s ap[4];
#pragma unroll
            for (int m = 0; m < 4; m++)
                ap[m] = *(const v8s*)(&Ps[cur][(m * 16 + l15) * 72 + kk2 * 32 +
                                               quad * 8]);
            v8s bva = kk2 ? bv10 : bv00;
            v8s bvb = kk2 ? bv11 : bv01;
#pragma unroll
            for (int m = 0; m < 4; m++) {
                oacc[m][0] = __builtin_amdgcn_mfma_f32_16x16x32_bf16(
                    ap[m], bva, oacc[m][0], 0, 0, 0);
                oacc[m][1] = __builtin_amdgcn_mfma_f32_16x16x32_bf16(
                    ap[m], bvb, oacc[m][1], 0, 0, 0);
            }
        }
        cur ^= 1;
        int tmp = c0;
        c0 = c1;
        c1 = c2;
        c2 = tmp;
    }
#pragma unroll
    for (int j = 0; j < 16; j++) {
        float s = sum16[j];
        s += __shfl_xor(s, 1);
        s += __shfl_xor(s, 2);
        s += __shfl_xor(s, 4);
        s += __shfl_xor(s, 8);
        sum16[j] = s;
    }
    if (l15 == 0) {
#pragma unroll
        for (int i = 0; i < 4; i++)
#pragma unroll
            for (int r2 = 0; r2 < 4; r2++)
                sred[w * 64 + i * 16 + quad * 4 + r2] = sum16[i * 4 + r2];
    }
    __syncthreads();
    if (tid < 64)
        sinv[tid] =
            1.f / (sred[tid] + sred[64 + tid] + sred[128 + tid] + sred[192 + tid]);
    __syncthreads();
#pragma unroll
    for (int m = 0; m < 4; m++)
#pragma unroll
        for (int r2 = 0; r2 < 4; r2++) {
            float inv = sinv[m * 16 + quad * 4 + r2];
            int row = qt * 64 + m * 16 + quad * 4 + r2;
#pragma unroll
            for (int nbi = 0; nbi < 2; nbi++) {
                int d = h * HDn + (2 * w + nbi) * 16 + l15;
                O[((size_t)b * Tn + row) * Cn + d] = oacc[m][nbi][r2] * inv;
            }
        }
}

extern "C" void kernel_launch(void* const* d_in, const int* in_sizes, int n_in,
                              void* d_out, int out_size, void* d_ws,
                              size_t ws_size, hipStream_t stream) {
    const float* hidden = (const float*)d_in[0];
    const int* mask = (const int*)d_in[1];
    const float* wq = (const float*)d_in[2];
    const float* wk = (const float*)d_in[3];
    const float* wv = (const float*)d_in[4];
    const float* wo = (const float*)d_in[5];
    const float* qg = (const float*)d_in[6];
    const float* kg = (const float*)d_in[7];
    const float* cs = (const float*)d_in[8];
    const float* sn = (const float*)d_in[9];

    char* ws = (char*)d_ws;
    int8_t* q8 = (int8_t*)(ws);                  // 24 MiB: wq,wk,wv,wo + hidden
    float* sAll = (float*)(ws + 25165824);       // 12288 fp32 scales
    u16* qb = (u16*)(ws + 25214976);             // Q bf16 (B,T,C)
    u16* kb = (u16*)(ws + 41992192);             // K bf16
    u16* vt = (u16*)(ws + 75546624);             // V^T bf16 (B,H,HD,T)
    float* Obuf = (float*)(ws + 92323840);       // O fp32 (B,T,C)
    int8_t* hid8 = q8 + 16777216;                // hidden int8 (reused for O)
    float* sx = sAll + 8192;                     // hidden scales (reused for O)

    quant_all<<<12288, 256, 0, stream>>>(wq, wk, wv, wo, hidden, q8, sAll);

    // z=0 -> Q bf16 (qb), z=1 -> K bf16 (kb), z=2 -> V written TRANSPOSED to vt
    gemm_i8<<<dim3(512, 3), 256, 0, stream>>>(hid8, q8, sx, sAll, (void*)qb,
                                              4194304LL, 2048LL, 8388608LL, 0,
                                              vt);

    norm_rope2<<<8192, 256, 0, stream>>>(qb, kb, qg, kg, cs, sn);

    flash<<<dim3(1024), 256, 0, stream>>>(qb, kb, vt, mask, Obuf);

    quant_rows<<<4096, 256, 0, stream>>>(Obuf, hid8, sx);
    gemm_i8<<<dim3(512, 1), 256, 0, stream>>>(hid8, q8 + 12582912, sx,
                                              sAll + 6144, d_out, 0LL, 0LL,
                                              0LL, 1, nullptr);
}